// Round 1
// baseline (26306.052 us; speedup 1.0000x reference)
//
#include <hip/hip_runtime.h>
#include <hip/hip_bf16.h>
#include <math.h>

#define LNUM 12
#define HNUM 12
#define EDIM 768
#define VDIM 50257
#define BDIM 2
#define TDIM 1024
#define BT (BDIM*TDIM)
#define E3 (3*EDIM)
#define E4 (4*EDIM)

// ---------------------------------------------------------------- helpers
__device__ __forceinline__ float gelu_f(float x) {
    float u = 0.7978845608028654f * (x + 0.044715f * x * x * x);
    return 0.5f * x * (1.0f + tanhf(u));
}

// ---------------------------------------------------------------- embedding
__global__ __launch_bounds__(256) void embed_kernel(
    const int* __restrict__ idx, const float* __restrict__ wte,
    const float* __restrict__ wpe, float* __restrict__ x)
{
    const int row = blockIdx.x;           // 0..BT-1
    const int t = row % TDIM;
    const int tok = idx[row];
    const float* we = wte + (size_t)tok * EDIM;
    const float* pe = wpe + (size_t)t * EDIM;
    float* xr = x + (size_t)row * EDIM;
    for (int e = threadIdx.x; e < EDIM; e += 256) xr[e] = we[e] + pe[e];
}

// ---------------------------------------------------------------- layernorm
__global__ __launch_bounds__(256) void ln_kernel(
    const float* __restrict__ in, const float* __restrict__ w,
    const float* __restrict__ b, float* __restrict__ out)
{
    const int row = blockIdx.x, tid = threadIdx.x;
    const float* xr = in + (size_t)row * EDIM;
    float v0 = xr[tid], v1 = xr[tid + 256], v2 = xr[tid + 512];
    float s = v0 + v1 + v2;
    __shared__ float red[8];
    const int lane = tid & 63, wid = tid >> 6;
    #pragma unroll
    for (int off = 32; off; off >>= 1) s += __shfl_xor(s, off);
    if (lane == 0) red[wid] = s;
    __syncthreads();
    const float mean = (red[0] + red[1] + red[2] + red[3]) * (1.0f / EDIM);
    float d0 = v0 - mean, d1 = v1 - mean, d2 = v2 - mean;
    float s2 = d0 * d0 + d1 * d1 + d2 * d2;
    #pragma unroll
    for (int off = 32; off; off >>= 1) s2 += __shfl_xor(s2, off);
    if (lane == 0) red[4 + wid] = s2;
    __syncthreads();
    const float var = (red[4] + red[5] + red[6] + red[7]) * (1.0f / EDIM);
    const float inv = rsqrtf(var + 1e-5f);
    float* orow = out + (size_t)row * EDIM;
    orow[tid]       = d0 * inv * w[tid]       + b[tid];
    orow[tid + 256] = d1 * inv * w[tid + 256] + b[tid + 256];
    orow[tid + 512] = d2 * inv * w[tid + 512] + b[tid + 512];
}

// ---------------------------------------------------------------- GEMM
// C[M,N] = act( A[M,K] @ B + bias ) (+ res)
// BTR=false: B is [K,N] row-major.  BTR=true: B is [N,K] row-major (B^T GEMM).
// 128x128 tile, BK=8, 256 threads, 8x8 per thread. M,K multiples of 128/8.
template<bool GELU_F, bool RES_F, bool BTR>
__global__ __launch_bounds__(256) void gemm_kernel(
    const float* __restrict__ A, const float* __restrict__ Bm,
    const float* __restrict__ bias, const float* __restrict__ res,
    float* __restrict__ C, int M, int N, int K)
{
    __shared__ float As[8][128];
    __shared__ float Bs[8][128];
    const int tid = threadIdx.x;
    const int tx = tid & 15, ty = tid >> 4;
    const int m0 = blockIdx.y * 128, n0 = blockIdx.x * 128;

    float acc[8][8];
    #pragma unroll
    for (int i = 0; i < 8; i++) {
        #pragma unroll
        for (int j = 0; j < 8; j++) acc[i][j] = 0.f;
    }

    const int lrow = tid >> 1;         // 0..127 (A tile & B^T tile row)
    const int lkq  = (tid & 1) * 4;    // 0 or 4
    const int bk   = tid >> 5;         // 0..7   (B[K,N] tile row)
    const int bnq  = (tid & 31) * 4;   // 0..124

    for (int k0 = 0; k0 < K; k0 += 8) {
        float4 av = *(const float4*)(A + (size_t)(m0 + lrow) * K + k0 + lkq);
        float4 bv;
        if (BTR) {
            const int nr = n0 + lrow;
            bv = (nr < N) ? *(const float4*)(Bm + (size_t)nr * K + k0 + lkq)
                          : make_float4(0.f, 0.f, 0.f, 0.f);
        } else {
            bv = *(const float4*)(Bm + (size_t)(k0 + bk) * N + n0 + bnq);
        }
        __syncthreads();
        As[lkq + 0][lrow] = av.x; As[lkq + 1][lrow] = av.y;
        As[lkq + 2][lrow] = av.z; As[lkq + 3][lrow] = av.w;
        if (BTR) {
            Bs[lkq + 0][lrow] = bv.x; Bs[lkq + 1][lrow] = bv.y;
            Bs[lkq + 2][lrow] = bv.z; Bs[lkq + 3][lrow] = bv.w;
        } else {
            *(float4*)&Bs[bk][bnq] = bv;
        }
        __syncthreads();
        #pragma unroll
        for (int kk = 0; kk < 8; kk++) {
            float a[8], bb[8];
            *(float4*)&a[0]  = *(const float4*)&As[kk][ty * 8];
            *(float4*)&a[4]  = *(const float4*)&As[kk][ty * 8 + 4];
            *(float4*)&bb[0] = *(const float4*)&Bs[kk][tx * 8];
            *(float4*)&bb[4] = *(const float4*)&Bs[kk][tx * 8 + 4];
            #pragma unroll
            for (int i = 0; i < 8; i++) {
                #pragma unroll
                for (int j = 0; j < 8; j++)
                    acc[i][j] = fmaf(a[i], bb[j], acc[i][j]);
            }
        }
    }

    #pragma unroll
    for (int i = 0; i < 8; i++) {
        const int m = m0 + ty * 8 + i;
        #pragma unroll
        for (int j = 0; j < 8; j++) {
            const int n = n0 + tx * 8 + j;
            if (n < N) {
                float v = acc[i][j];
                if (bias) v += bias[n];
                if (GELU_F) v = gelu_f(v);
                if (RES_F) v += res[(size_t)m * N + n];
                C[(size_t)m * N + n] = v;
            }
        }
    }
}

// ---------------------------------------------------------------- attention
// one block per (q, h, b); qkv layout: [B*T][3E], q at h*64, k at E+h*64, v at 2E+h*64
__global__ __launch_bounds__(256) void attn_kernel(
    const float* __restrict__ qkv, float* __restrict__ y)
{
    const int qi = blockIdx.x, h = blockIdx.y, b = blockIdx.z;
    const int tid = threadIdx.x, lane = tid & 63, wid = tid >> 6;
    __shared__ float qs[64];
    __shared__ float s[TDIM];
    __shared__ float red[8];
    __shared__ float ys[4][64];
    const size_t base = (size_t)b * TDIM * E3;
    if (tid < 64) qs[tid] = qkv[base + (size_t)qi * E3 + h * 64 + tid];
    __syncthreads();
    const int n = qi + 1;
    // QK^T (one wave per k row, lanes over d, shuffle reduce)
    for (int k = wid; k < n; k += 4) {
        float p = qs[lane] * qkv[base + (size_t)k * E3 + EDIM + h * 64 + lane];
        #pragma unroll
        for (int off = 32; off; off >>= 1) p += __shfl_xor(p, off);
        if (lane == 0) s[k] = p * 0.125f;   // 1/sqrt(64)
    }
    __syncthreads();
    // softmax
    float mx = -1e30f;
    for (int k = tid; k < n; k += 256) mx = fmaxf(mx, s[k]);
    #pragma unroll
    for (int off = 32; off; off >>= 1) mx = fmaxf(mx, __shfl_xor(mx, off));
    if (lane == 0) red[wid] = mx;
    __syncthreads();
    mx = fmaxf(fmaxf(red[0], red[1]), fmaxf(red[2], red[3]));
    float sm = 0.f;
    for (int k = tid; k < n; k += 256) { float e = __expf(s[k] - mx); s[k] = e; sm += e; }
    #pragma unroll
    for (int off = 32; off; off >>= 1) sm += __shfl_xor(sm, off);
    if (lane == 0) red[4 + wid] = sm;
    __syncthreads();
    const float inv = 1.0f / (red[4] + red[5] + red[6] + red[7]);
    // AV
    const int d = tid & 63, c = tid >> 6;
    float acc = 0.f;
    for (int k = c; k < n; k += 4)
        acc += s[k] * qkv[base + (size_t)k * E3 + 2 * EDIM + h * 64 + d];
    ys[c][d] = acc;
    __syncthreads();
    if (tid < 64)
        y[((size_t)(b * TDIM + qi)) * EDIM + h * 64 + tid] =
            (ys[0][tid] + ys[1][tid] + ys[2][tid] + ys[3][tid]) * inv;
}

// ---------------------------------------------------------------- loss
__global__ __launch_bounds__(256) void nll_kernel(
    const float* __restrict__ logits, const int* __restrict__ targets,
    float* __restrict__ rr)
{
    const int row = blockIdx.x, tid = threadIdx.x;
    const float* lr = logits + (size_t)row * VDIM;
    float ml = -1e30f, sl = 0.f;
    for (int v = tid; v < VDIM; v += 256) {
        float xv = lr[v];
        if (xv > ml) { sl = sl * __expf(ml - xv) + 1.0f; ml = xv; }
        else sl += __expf(xv - ml);
    }
    #pragma unroll
    for (int off = 32; off; off >>= 1) {
        float om = __shfl_xor(ml, off), os = __shfl_xor(sl, off);
        if (om > ml) { sl = sl * __expf(ml - om) + os; ml = om; }
        else sl += os * __expf(om - ml);
    }
    __shared__ float rm[4], rs[4];
    const int lane = tid & 63, wid = tid >> 6;
    if (lane == 0) { rm[wid] = ml; rs[wid] = sl; }
    __syncthreads();
    if (tid == 0) {
        float M = rm[0], S = rs[0];
        for (int i = 1; i < 4; i++) {
            float om = rm[i], os = rs[i];
            if (om > M) { S = S * __expf(M - om) + os; M = om; }
            else S += os * __expf(om - M);
        }
        rr[row] = -(lr[targets[row]] - M - logf(S));
    }
}

__global__ __launch_bounds__(256) void loss_reduce_kernel(
    const float* __restrict__ rr, float* __restrict__ out)
{
    const int tid = threadIdx.x;
    float s = 0.f;
    for (int i = tid; i < BT; i += 256) s += rr[i];
    #pragma unroll
    for (int off = 32; off; off >>= 1) s += __shfl_xor(s, off);
    __shared__ float red[4];
    if ((tid & 63) == 0) red[tid >> 6] = s;
    __syncthreads();
    if (tid == 0) out[0] = (red[0] + red[1] + red[2] + red[3]) * (1.0f / BT);
}

// ---------------------------------------------------------------- launch
extern "C" void kernel_launch(void* const* d_in, const int* in_sizes, int n_in,
                              void* d_out, int out_size, void* d_ws, size_t ws_size,
                              hipStream_t stream)
{
    const int*   idx     = (const int*)d_in[0];
    const int*   targets = (const int*)d_in[1];
    const float* wte     = (const float*)d_in[2];
    const float* wpe     = (const float*)d_in[3];
    const float* ln1_w   = (const float*)d_in[4];
    const float* ln1_b   = (const float*)d_in[5];
    const float* attn_w  = (const float*)d_in[6];
    const float* attn_b  = (const float*)d_in[7];
    const float* proj_w  = (const float*)d_in[8];
    const float* proj_b  = (const float*)d_in[9];
    const float* ln2_w   = (const float*)d_in[10];
    const float* ln2_b   = (const float*)d_in[11];
    const float* fc_w    = (const float*)d_in[12];
    const float* fc_b    = (const float*)d_in[13];
    const float* fcp_w   = (const float*)d_in[14];
    const float* fcp_b   = (const float*)d_in[15];
    const float* lnf_w   = (const float*)d_in[16];
    const float* lnf_b   = (const float*)d_in[17];

    float* logits = (float*)d_out;
    float* ws  = (float*)d_ws;
    float* x   = ws;                        // BT*E
    float* xn  = x  + (size_t)BT * EDIM;    // BT*E
    float* big = xn + (size_t)BT * EDIM;    // BT*4E (qkv then MLP h)
    float* y   = big + (size_t)BT * E4;     // BT*E
    float* rr  = y  + (size_t)BT * EDIM;    // BT

    embed_kernel<<<BT, 256, 0, stream>>>(idx, wte, wpe, x);

    for (int l = 0; l < LNUM; ++l) {
        ln_kernel<<<BT, 256, 0, stream>>>(x, ln1_w + (size_t)l * EDIM,
                                          ln1_b + (size_t)l * EDIM, xn);
        gemm_kernel<false, false, false><<<dim3(E3 / 128, BT / 128), 256, 0, stream>>>(
            xn, attn_w + (size_t)l * EDIM * E3, attn_b + (size_t)l * E3,
            nullptr, big, BT, E3, EDIM);
        attn_kernel<<<dim3(TDIM, HNUM, BDIM), 256, 0, stream>>>(big, y);
        gemm_kernel<false, true, false><<<dim3(EDIM / 128, BT / 128), 256, 0, stream>>>(
            y, proj_w + (size_t)l * EDIM * EDIM, proj_b + (size_t)l * EDIM,
            x, x, BT, EDIM, EDIM);
        ln_kernel<<<BT, 256, 0, stream>>>(x, ln2_w + (size_t)l * EDIM,
                                          ln2_b + (size_t)l * EDIM, xn);
        gemm_kernel<true, false, false><<<dim3(E4 / 128, BT / 128), 256, 0, stream>>>(
            xn, fc_w + (size_t)l * EDIM * E4, fc_b + (size_t)l * E4,
            nullptr, big, BT, E4, EDIM);
        gemm_kernel<false, true, false><<<dim3(EDIM / 128, BT / 128), 256, 0, stream>>>(
            big, fcp_w + (size_t)l * E4 * EDIM, fcp_b + (size_t)l * EDIM,
            x, x, BT, EDIM, E4);
    }

    ln_kernel<<<BT, 256, 0, stream>>>(x, lnf_w, lnf_b, xn);
    gemm_kernel<false, false, true><<<dim3((VDIM + 127) / 128, BT / 128), 256, 0, stream>>>(
        xn, wte, nullptr, nullptr, logits, BT, VDIM, EDIM);
    nll_kernel<<<BT, 256, 0, stream>>>(logits, targets, rr);
    loss_reduce_kernel<<<1, 256, 0, stream>>>(rr, logits + (size_t)BT * VDIM);
}

// Round 2
// 14754.385 us; speedup vs baseline: 1.7829x; 1.7829x over previous
//
#include <hip/hip_runtime.h>
#include <hip/hip_bf16.h>
#include <math.h>

#define LNUM 12
#define HNUM 12
#define EDIM 768
#define VDIM 50257
#define BDIM 2
#define TDIM 1024
#define BT (BDIM*TDIM)
#define E3 (3*EDIM)
#define E4 (4*EDIM)

typedef __bf16 bf16x8 __attribute__((ext_vector_type(8)));
typedef float f32x4 __attribute__((ext_vector_type(4)));

__device__ __forceinline__ float gelu_f(float x) {
    float u = 0.7978845608028654f * (x + 0.044715f * x * x * x);
    return 0.5f * x * (1.0f + tanhf(u));
}

// async global->LDS, 16B per lane
__device__ __forceinline__ void gl16(const void* g, void* l) {
    __builtin_amdgcn_global_load_lds(
        (const __attribute__((address_space(1))) unsigned int*)g,
        (__attribute__((address_space(3))) unsigned int*)l,
        16, 0, 0);
}

// ---------------------------------------------------------------- embedding
__global__ __launch_bounds__(256) void embed_kernel(
    const int* __restrict__ idx, const float* __restrict__ wte,
    const float* __restrict__ wpe, float* __restrict__ x)
{
    const int row = blockIdx.x;
    const int t = row % TDIM;
    const int tok = idx[row];
    const float* we = wte + (size_t)tok * EDIM;
    const float* pe = wpe + (size_t)t * EDIM;
    float* xr = x + (size_t)row * EDIM;
    for (int e = threadIdx.x; e < EDIM; e += 256) xr[e] = we[e] + pe[e];
}

// ---------------------------------------------------------------- layernorm (bf16 out)
__global__ __launch_bounds__(256) void ln_kernel(
    const float* __restrict__ in, const float* __restrict__ w,
    const float* __restrict__ b, __bf16* __restrict__ out)
{
    const int row = blockIdx.x, tid = threadIdx.x;
    const float* xr = in + (size_t)row * EDIM;
    float v0 = xr[tid], v1 = xr[tid + 256], v2 = xr[tid + 512];
    float s = v0 + v1 + v2;
    __shared__ float red[8];
    const int lane = tid & 63, wid = tid >> 6;
    #pragma unroll
    for (int off = 32; off; off >>= 1) s += __shfl_xor(s, off);
    if (lane == 0) red[wid] = s;
    __syncthreads();
    const float mean = (red[0] + red[1] + red[2] + red[3]) * (1.0f / EDIM);
    float d0 = v0 - mean, d1 = v1 - mean, d2 = v2 - mean;
    float s2 = d0 * d0 + d1 * d1 + d2 * d2;
    #pragma unroll
    for (int off = 32; off; off >>= 1) s2 += __shfl_xor(s2, off);
    if (lane == 0) red[4 + wid] = s2;
    __syncthreads();
    const float var = (red[4] + red[5] + red[6] + red[7]) * (1.0f / EDIM);
    const float inv = rsqrtf(var + 1e-5f);
    __bf16* orow = out + (size_t)row * EDIM;
    orow[tid]       = (__bf16)(d0 * inv * w[tid]       + b[tid]);
    orow[tid + 256] = (__bf16)(d1 * inv * w[tid + 256] + b[tid + 256]);
    orow[tid + 512] = (__bf16)(d2 * inv * w[tid + 512] + b[tid + 512]);
}

// ------------------------------------------------- weight convert: f32 [K][N] -> bf16 [N][K]
__global__ __launch_bounds__(256) void convt_kernel(
    const float* __restrict__ in, __bf16* __restrict__ out, int K, int N)
{
    __shared__ float t[32][33];
    const int n0 = blockIdx.x * 32, k0 = blockIdx.y * 32;
    const int tx = threadIdx.x & 31, ty = threadIdx.x >> 5;
    #pragma unroll
    for (int r = ty; r < 32; r += 8)
        t[r][tx] = in[(size_t)(k0 + r) * N + n0 + tx];
    __syncthreads();
    #pragma unroll
    for (int r = ty; r < 32; r += 8)
        out[(size_t)(n0 + r) * K + k0 + tx] = (__bf16)t[tx][r];
}

// ------------------------------------------------- elementwise f32 -> bf16 (wte)
__global__ __launch_bounds__(256) void cvt_kernel(
    const float* __restrict__ in, __bf16* __restrict__ out, long n4)
{
    for (long i = blockIdx.x * 256L + threadIdx.x; i < n4; i += (long)gridDim.x * 256L) {
        float4 v = ((const float4*)in)[i];
        out[i * 4 + 0] = (__bf16)v.x;
        out[i * 4 + 1] = (__bf16)v.y;
        out[i * 4 + 2] = (__bf16)v.z;
        out[i * 4 + 3] = (__bf16)v.w;
    }
}

// ---------------------------------------------------------------- MFMA GEMM
// C[M,N] = act(A[M,K] @ Bt[N,K]^T + bias) (+res). A,Bt bf16 row-major (k-contiguous).
// 128x128 tile, BK=32, 4 waves (2x2), each wave 64x64 = 4x4 frags of 16x16x32.
// LDS XOR-swizzle: logical (row, kchunk c of 8 bf16) at phys byte row*64 + (c^((row>>1)&3))*16.
// global_load_lds writes linearly -> source address carries the inverse swizzle.
template<bool BIAS, bool GELU_, bool RES_, bool OUTBF, bool NGUARD>
__global__ __launch_bounds__(256) void mgemm(
    const __bf16* __restrict__ A, const __bf16* __restrict__ Bt,
    const float* __restrict__ bias, const float* __restrict__ res,
    void* __restrict__ Cout, int M, int N, int K)
{
    __shared__ __align__(16) __bf16 As[4096];   // 128 rows x 32 k
    __shared__ __align__(16) __bf16 Bs[4096];
    const int tid = threadIdx.x;
    const int lane = tid & 63;
    const int wave = tid >> 6;
    const int wr = wave >> 1, wc = wave & 1;
    const int m0 = blockIdx.y * 128;
    const int n0 = blockIdx.x * 128;

    // staging: thread covers (row = tid>>2, phys slot = tid&3); logical chunk = slot ^ sw(row)
    const int srow = tid >> 2;                       // 0..63 (and +64 for 2nd inst)
    const int c0 = (tid & 3) ^ ((srow >> 1) & 3);    // same for row srow and srow+64

    const __bf16* ga0 = A + (size_t)(m0 + srow) * K + c0 * 8;
    const __bf16* ga1 = ga0 + (size_t)64 * K;
    int nr0 = n0 + srow, nr1 = n0 + srow + 64;
    if (NGUARD) { nr0 = nr0 < N ? nr0 : N - 1; nr1 = nr1 < N ? nr1 : N - 1; }
    const __bf16* gb0 = Bt + (size_t)nr0 * K + c0 * 8;
    const __bf16* gb1 = Bt + (size_t)nr1 * K + c0 * 8;

    char* const lA0 = (char*)As + tid * 16;
    char* const lA1 = (char*)As + 4096 + tid * 16;
    char* const lB0 = (char*)Bs + tid * 16;
    char* const lB1 = (char*)Bs + 4096 + tid * 16;

    // fragment read offsets (swizzled)
    const int fr = lane & 15;            // A row / B col within frag
    const int g = lane >> 4;             // k-group (8 bf16 each)
    const int slot = ((g ^ ((lane >> 1) & 3)) << 4);
    const int offA = (wr * 64 + fr) * 64 + slot;
    const int offB = (wc * 64 + fr) * 64 + slot;

    f32x4 acc[4][4];
    #pragma unroll
    for (int i = 0; i < 4; i++)
        #pragma unroll
        for (int j = 0; j < 4; j++) acc[i][j] = (f32x4){0.f, 0.f, 0.f, 0.f};

    for (int k0 = 0; k0 < K; k0 += 32) {
        gl16(ga0 + k0, lA0);
        gl16(ga1 + k0, lA1);
        gl16(gb0 + k0, lB0);
        gl16(gb1 + k0, lB1);
        __syncthreads();                 // compiler drains vmcnt before barrier
        bf16x8 af[4], bfr[4];
        #pragma unroll
        for (int i = 0; i < 4; i++)
            af[i] = *(const bf16x8*)((const char*)As + offA + i * 1024);
        #pragma unroll
        for (int j = 0; j < 4; j++)
            bfr[j] = *(const bf16x8*)((const char*)Bs + offB + j * 1024);
        #pragma unroll
        for (int i = 0; i < 4; i++)
            #pragma unroll
            for (int j = 0; j < 4; j++)
                acc[i][j] = __builtin_amdgcn_mfma_f32_16x16x32_bf16(af[i], bfr[j], acc[i][j], 0, 0, 0);
        __syncthreads();                 // all waves done reading before next overwrite
    }

    // epilogue: C/D frag: col = lane&15, row = (lane>>4)*4 + reg
    const int crow = g * 4;
    #pragma unroll
    for (int i = 0; i < 4; i++) {
        #pragma unroll
        for (int r = 0; r < 4; r++) {
            const int m = m0 + wr * 64 + i * 16 + crow + r;
            #pragma unroll
            for (int j = 0; j < 4; j++) {
                const int n = n0 + wc * 64 + j * 16 + fr;
                if (!NGUARD || n < N) {
                    float v = acc[i][j][r];
                    if (BIAS) v += bias[n];
                    if (GELU_) v = gelu_f(v);
                    if (RES_) v += res[(size_t)m * N + n];
                    if (OUTBF) ((__bf16*)Cout)[(size_t)m * N + n] = (__bf16)v;
                    else       ((float*)Cout)[(size_t)m * N + n] = v;
                }
            }
        }
    }
}

// ---------------------------------------------------------------- attention (f32 in, bf16 out)
__global__ __launch_bounds__(256) void attn_kernel(
    const float* __restrict__ qkv, __bf16* __restrict__ y)
{
    const int qi = blockIdx.x, h = blockIdx.y, b = blockIdx.z;
    const int tid = threadIdx.x, lane = tid & 63, wid = tid >> 6;
    __shared__ float qs[64];
    __shared__ float s[TDIM];
    __shared__ float red[8];
    __shared__ float ys[4][64];
    const size_t base = (size_t)b * TDIM * E3;
    if (tid < 64) qs[tid] = qkv[base + (size_t)qi * E3 + h * 64 + tid];
    __syncthreads();
    const int n = qi + 1;
    for (int k = wid; k < n; k += 4) {
        float p = qs[lane] * qkv[base + (size_t)k * E3 + EDIM + h * 64 + lane];
        #pragma unroll
        for (int off = 32; off; off >>= 1) p += __shfl_xor(p, off);
        if (lane == 0) s[k] = p * 0.125f;
    }
    __syncthreads();
    float mx = -1e30f;
    for (int k = tid; k < n; k += 256) mx = fmaxf(mx, s[k]);
    #pragma unroll
    for (int off = 32; off; off >>= 1) mx = fmaxf(mx, __shfl_xor(mx, off));
    if (lane == 0) red[wid] = mx;
    __syncthreads();
    mx = fmaxf(fmaxf(red[0], red[1]), fmaxf(red[2], red[3]));
    float sm = 0.f;
    for (int k = tid; k < n; k += 256) { float e = __expf(s[k] - mx); s[k] = e; sm += e; }
    #pragma unroll
    for (int off = 32; off; off >>= 1) sm += __shfl_xor(sm, off);
    if (lane == 0) red[4 + wid] = sm;
    __syncthreads();
    const float inv = 1.0f / (red[4] + red[5] + red[6] + red[7]);
    const int d = tid & 63, c = tid >> 6;
    float acc = 0.f;
    for (int k = c; k < n; k += 4)
        acc += s[k] * qkv[base + (size_t)k * E3 + 2 * EDIM + h * 64 + d];
    ys[c][d] = acc;
    __syncthreads();
    if (tid < 64)
        y[((size_t)(b * TDIM + qi)) * EDIM + h * 64 + tid] =
            (__bf16)((ys[0][tid] + ys[1][tid] + ys[2][tid] + ys[3][tid]) * inv);
}

// ---------------------------------------------------------------- loss
__global__ __launch_bounds__(256) void nll_kernel(
    const float* __restrict__ logits, const int* __restrict__ targets,
    float* __restrict__ rr)
{
    const int row = blockIdx.x, tid = threadIdx.x;
    const float* lr = logits + (size_t)row * VDIM;
    float ml = -1e30f, sl = 0.f;
    for (int v = tid; v < VDIM; v += 256) {
        float xv = lr[v];
        if (xv > ml) { sl = sl * __expf(ml - xv) + 1.0f; ml = xv; }
        else sl += __expf(xv - ml);
    }
    #pragma unroll
    for (int off = 32; off; off >>= 1) {
        float om = __shfl_xor(ml, off), os = __shfl_xor(sl, off);
        if (om > ml) { sl = sl * __expf(ml - om) + os; ml = om; }
        else sl += os * __expf(om - ml);
    }
    __shared__ float rm[4], rs[4];
    const int lane = tid & 63, wid = tid >> 6;
    if (lane == 0) { rm[wid] = ml; rs[wid] = sl; }
    __syncthreads();
    if (tid == 0) {
        float M = rm[0], S = rs[0];
        for (int i = 1; i < 4; i++) {
            float om = rm[i], os = rs[i];
            if (om > M) { S = S * __expf(M - om) + os; M = om; }
            else S += os * __expf(om - M);
        }
        rr[row] = -(lr[targets[row]] - M - logf(S));
    }
}

__global__ __launch_bounds__(256) void loss_reduce_kernel(
    const float* __restrict__ rr, float* __restrict__ out)
{
    const int tid = threadIdx.x;
    float s = 0.f;
    for (int i = tid; i < BT; i += 256) s += rr[i];
    #pragma unroll
    for (int off = 32; off; off >>= 1) s += __shfl_xor(s, off);
    __shared__ float red[4];
    if ((tid & 63) == 0) red[tid >> 6] = s;
    __syncthreads();
    if (tid == 0) out[0] = (red[0] + red[1] + red[2] + red[3]) * (1.0f / BT);
}

// ---------------------------------------------------------------- launch
extern "C" void kernel_launch(void* const* d_in, const int* in_sizes, int n_in,
                              void* d_out, int out_size, void* d_ws, size_t ws_size,
                              hipStream_t stream)
{
    const int*   idx     = (const int*)d_in[0];
    const int*   targets = (const int*)d_in[1];
    const float* wte     = (const float*)d_in[2];
    const float* wpe     = (const float*)d_in[3];
    const float* ln1_w   = (const float*)d_in[4];
    const float* ln1_b   = (const float*)d_in[5];
    const float* attn_w  = (const float*)d_in[6];
    const float* attn_b  = (const float*)d_in[7];
    const float* proj_w  = (const float*)d_in[8];
    const float* proj_b  = (const float*)d_in[9];
    const float* ln2_w   = (const float*)d_in[10];
    const float* ln2_b   = (const float*)d_in[11];
    const float* fc_w    = (const float*)d_in[12];
    const float* fc_b    = (const float*)d_in[13];
    const float* fcp_w   = (const float*)d_in[14];
    const float* fcp_b   = (const float*)d_in[15];
    const float* lnf_w   = (const float*)d_in[16];
    const float* lnf_b   = (const float*)d_in[17];

    float* logits = (float*)d_out;

    char* wp = (char*)d_ws;
    float*  x     = (float*)wp;   wp += (size_t)BT * EDIM * 4;
    float*  qkv   = (float*)wp;   wp += (size_t)BT * E3 * 4;
    __bf16* xnbf  = (__bf16*)wp;  wp += (size_t)BT * EDIM * 2;
    __bf16* ybf   = (__bf16*)wp;  wp += (size_t)BT * EDIM * 2;
    __bf16* hbf   = (__bf16*)wp;  wp += (size_t)BT * E4 * 2;
    __bf16* wqkvb = (__bf16*)wp;  wp += (size_t)EDIM * E3 * 2;
    __bf16* wprjb = (__bf16*)wp;  wp += (size_t)EDIM * EDIM * 2;
    __bf16* wfcb  = (__bf16*)wp;  wp += (size_t)EDIM * E4 * 2;
    __bf16* wfpb  = (__bf16*)wp;  wp += (size_t)E4 * EDIM * 2;
    __bf16* wteb  = (__bf16*)wp;  wp += (size_t)VDIM * EDIM * 2;
    float*  rr    = (float*)wp;

    embed_kernel<<<BT, 256, 0, stream>>>(idx, wte, wpe, x);
    cvt_kernel<<<2048, 256, 0, stream>>>(wte, wteb, (long)VDIM * EDIM / 4);

    for (int l = 0; l < LNUM; ++l) {
        ln_kernel<<<BT, 256, 0, stream>>>(x, ln1_w + (size_t)l * EDIM,
                                          ln1_b + (size_t)l * EDIM, xnbf);
        convt_kernel<<<dim3(E3 / 32, EDIM / 32), 256, 0, stream>>>(
            attn_w + (size_t)l * EDIM * E3, wqkvb, EDIM, E3);
        mgemm<true, false, false, false, false><<<dim3(E3 / 128, BT / 128), 256, 0, stream>>>(
            xnbf, wqkvb, attn_b + (size_t)l * E3, nullptr, qkv, BT, E3, EDIM);
        attn_kernel<<<dim3(TDIM, HNUM, BDIM), 256, 0, stream>>>(qkv, ybf);
        convt_kernel<<<dim3(EDIM / 32, EDIM / 32), 256, 0, stream>>>(
            proj_w + (size_t)l * EDIM * EDIM, wprjb, EDIM, EDIM);
        mgemm<true, false, true, false, false><<<dim3(EDIM / 128, BT / 128), 256, 0, stream>>>(
            ybf, wprjb, proj_b + (size_t)l * EDIM, x, x, BT, EDIM, EDIM);
        ln_kernel<<<BT, 256, 0, stream>>>(x, ln2_w + (size_t)l * EDIM,
                                          ln2_b + (size_t)l * EDIM, xnbf);
        convt_kernel<<<dim3(E4 / 32, EDIM / 32), 256, 0, stream>>>(
            fc_w + (size_t)l * EDIM * E4, wfcb, EDIM, E4);
        mgemm<true, true, false, true, false><<<dim3(E4 / 128, BT / 128), 256, 0, stream>>>(
            xnbf, wfcb, fc_b + (size_t)l * E4, nullptr, hbf, BT, E4, EDIM);
        convt_kernel<<<dim3(EDIM / 32, E4 / 32), 256, 0, stream>>>(
            fcp_w + (size_t)l * E4 * EDIM, wfpb, E4, EDIM);
        mgemm<true, false, true, false, false><<<dim3(EDIM / 128, BT / 128), 256, 0, stream>>>(
            hbf, wfpb, fcp_b + (size_t)l * EDIM, x, x, BT, EDIM, E4);
    }

    ln_kernel<<<BT, 256, 0, stream>>>(x, lnf_w, lnf_b, xnbf);
    mgemm<false, false, false, false, true><<<dim3((VDIM + 127) / 128, BT / 128), 256, 0, stream>>>(
        xnbf, wteb, nullptr, nullptr, logits, BT, VDIM, EDIM);
    nll_kernel<<<BT, 256, 0, stream>>>(logits, targets, rr);
    loss_reduce_kernel<<<1, 256, 0, stream>>>(rr, logits + (size_t)BT * VDIM);
}

// Round 3
// 2969.088 us; speedup vs baseline: 8.8600x; 4.9693x over previous
//
#include <hip/hip_runtime.h>
#include <hip/hip_bf16.h>
#include <math.h>

#define LNUM 12
#define HNUM 12
#define EDIM 768
#define VDIM 50257
#define BDIM 2
#define TDIM 1024
#define BT (BDIM*TDIM)
#define E3 (3*EDIM)
#define E4 (4*EDIM)

typedef __bf16 bf16x8 __attribute__((ext_vector_type(8)));
typedef float f32x4 __attribute__((ext_vector_type(4)));

__device__ __forceinline__ float gelu_f(float x) {
    float u = 0.7978845608028654f * (x + 0.044715f * x * x * x);
    return 0.5f * x * (1.0f + tanhf(u));
}

// async global->LDS, 16B per lane
__device__ __forceinline__ void gl16(const void* g, void* l) {
    __builtin_amdgcn_global_load_lds(
        (const __attribute__((address_space(1))) unsigned int*)g,
        (__attribute__((address_space(3))) unsigned int*)l,
        16, 0, 0);
}

// ---------------------------------------------------------------- embedding
__global__ __launch_bounds__(256) void embed_kernel(
    const int* __restrict__ idx, const float* __restrict__ wte,
    const float* __restrict__ wpe, float* __restrict__ x)
{
    const int row = blockIdx.x;
    const int t = row % TDIM;
    const int tok = idx[row];
    const float* we = wte + (size_t)tok * EDIM;
    const float* pe = wpe + (size_t)t * EDIM;
    float* xr = x + (size_t)row * EDIM;
    for (int e = threadIdx.x; e < EDIM; e += 256) xr[e] = we[e] + pe[e];
}

// ---------------------------------------------------------------- layernorm (bf16 out)
__global__ __launch_bounds__(256) void ln_kernel(
    const float* __restrict__ in, const float* __restrict__ w,
    const float* __restrict__ b, __bf16* __restrict__ out)
{
    const int row = blockIdx.x, tid = threadIdx.x;
    const float* xr = in + (size_t)row * EDIM;
    float v0 = xr[tid], v1 = xr[tid + 256], v2 = xr[tid + 512];
    float s = v0 + v1 + v2;
    __shared__ float red[8];
    const int lane = tid & 63, wid = tid >> 6;
    #pragma unroll
    for (int off = 32; off; off >>= 1) s += __shfl_xor(s, off);
    if (lane == 0) red[wid] = s;
    __syncthreads();
    const float mean = (red[0] + red[1] + red[2] + red[3]) * (1.0f / EDIM);
    float d0 = v0 - mean, d1 = v1 - mean, d2 = v2 - mean;
    float s2 = d0 * d0 + d1 * d1 + d2 * d2;
    #pragma unroll
    for (int off = 32; off; off >>= 1) s2 += __shfl_xor(s2, off);
    if (lane == 0) red[4 + wid] = s2;
    __syncthreads();
    const float var = (red[4] + red[5] + red[6] + red[7]) * (1.0f / EDIM);
    const float inv = rsqrtf(var + 1e-5f);
    __bf16* orow = out + (size_t)row * EDIM;
    orow[tid]       = (__bf16)(d0 * inv * w[tid]       + b[tid]);
    orow[tid + 256] = (__bf16)(d1 * inv * w[tid + 256] + b[tid + 256]);
    orow[tid + 512] = (__bf16)(d2 * inv * w[tid + 512] + b[tid + 512]);
}

// ------------------------------------------------- weight convert: f32 [K][N] -> bf16 [N][K]
__global__ __launch_bounds__(256) void convt_kernel(
    const float* __restrict__ in, __bf16* __restrict__ out, int K, int N)
{
    __shared__ float t[32][33];
    const int n0 = blockIdx.x * 32, k0 = blockIdx.y * 32;
    const int tx = threadIdx.x & 31, ty = threadIdx.x >> 5;
    #pragma unroll
    for (int r = ty; r < 32; r += 8)
        t[r][tx] = in[(size_t)(k0 + r) * N + n0 + tx];
    __syncthreads();
    #pragma unroll
    for (int r = ty; r < 32; r += 8)
        out[(size_t)(n0 + r) * K + k0 + tx] = (__bf16)t[tx][r];
}

// ------------------------------------------------- elementwise f32 -> bf16 (wte)
__global__ __launch_bounds__(256) void cvt_kernel(
    const float* __restrict__ in, __bf16* __restrict__ out, long n4)
{
    for (long i = blockIdx.x * 256L + threadIdx.x; i < n4; i += (long)gridDim.x * 256L) {
        float4 v = ((const float4*)in)[i];
        out[i * 4 + 0] = (__bf16)v.x;
        out[i * 4 + 1] = (__bf16)v.y;
        out[i * 4 + 2] = (__bf16)v.z;
        out[i * 4 + 3] = (__bf16)v.w;
    }
}

// ---------------------------------------------------------------- MFMA GEMM
// C[M,N] = act(A[M,K] @ Bt[N,K]^T + bias) (+res). A,Bt bf16 row-major (k-contiguous).
template<bool BIAS, bool GELU_, bool RES_, bool OUTBF, bool NGUARD>
__global__ __launch_bounds__(256) void mgemm(
    const __bf16* __restrict__ A, const __bf16* __restrict__ Bt,
    const float* __restrict__ bias, const float* __restrict__ res,
    void* __restrict__ Cout, int M, int N, int K)
{
    __shared__ __align__(16) __bf16 As[4096];   // 128 rows x 32 k
    __shared__ __align__(16) __bf16 Bs[4096];
    const int tid = threadIdx.x;
    const int lane = tid & 63;
    const int wave = tid >> 6;
    const int wr = wave >> 1, wc = wave & 1;
    const int m0 = blockIdx.y * 128;
    const int n0 = blockIdx.x * 128;

    const int srow = tid >> 2;
    const int c0 = (tid & 3) ^ ((srow >> 1) & 3);

    const __bf16* ga0 = A + (size_t)(m0 + srow) * K + c0 * 8;
    const __bf16* ga1 = ga0 + (size_t)64 * K;
    int nr0 = n0 + srow, nr1 = n0 + srow + 64;
    if (NGUARD) { nr0 = nr0 < N ? nr0 : N - 1; nr1 = nr1 < N ? nr1 : N - 1; }
    const __bf16* gb0 = Bt + (size_t)nr0 * K + c0 * 8;
    const __bf16* gb1 = Bt + (size_t)nr1 * K + c0 * 8;

    char* const lA0 = (char*)As + tid * 16;
    char* const lA1 = (char*)As + 4096 + tid * 16;
    char* const lB0 = (char*)Bs + tid * 16;
    char* const lB1 = (char*)Bs + 4096 + tid * 16;

    const int fr = lane & 15;
    const int g = lane >> 4;
    const int slot = ((g ^ ((lane >> 1) & 3)) << 4);
    const int offA = (wr * 64 + fr) * 64 + slot;
    const int offB = (wc * 64 + fr) * 64 + slot;

    f32x4 acc[4][4];
    #pragma unroll
    for (int i = 0; i < 4; i++)
        #pragma unroll
        for (int j = 0; j < 4; j++) acc[i][j] = (f32x4){0.f, 0.f, 0.f, 0.f};

    for (int k0 = 0; k0 < K; k0 += 32) {
        gl16(ga0 + k0, lA0);
        gl16(ga1 + k0, lA1);
        gl16(gb0 + k0, lB0);
        gl16(gb1 + k0, lB1);
        __syncthreads();
        bf16x8 af[4], bfr[4];
        #pragma unroll
        for (int i = 0; i < 4; i++)
            af[i] = *(const bf16x8*)((const char*)As + offA + i * 1024);
        #pragma unroll
        for (int j = 0; j < 4; j++)
            bfr[j] = *(const bf16x8*)((const char*)Bs + offB + j * 1024);
        #pragma unroll
        for (int i = 0; i < 4; i++)
            #pragma unroll
            for (int j = 0; j < 4; j++)
                acc[i][j] = __builtin_amdgcn_mfma_f32_16x16x32_bf16(af[i], bfr[j], acc[i][j], 0, 0, 0);
        __syncthreads();
    }

    const int crow = g * 4;
    #pragma unroll
    for (int i = 0; i < 4; i++) {
        #pragma unroll
        for (int r = 0; r < 4; r++) {
            const int m = m0 + wr * 64 + i * 16 + crow + r;
            #pragma unroll
            for (int j = 0; j < 4; j++) {
                const int n = n0 + wc * 64 + j * 16 + fr;
                if (!NGUARD || n < N) {
                    float v = acc[i][j][r];
                    if (BIAS) v += bias[n];
                    if (GELU_) v = gelu_f(v);
                    if (RES_) v += res[(size_t)m * N + n];
                    if (OUTBF) ((__bf16*)Cout)[(size_t)m * N + n] = (__bf16)v;
                    else       ((float*)Cout)[(size_t)m * N + n] = v;
                }
            }
        }
    }
}

// ---------------------------------------------------------------- flash attention (bf16 MFMA)
// grid (T/64, H, B), 256 threads = 4 waves; wave w owns q rows q0w..q0w+15.
// K-tile [64][64] and V^T-tile [64 d][64 k] staged in LDS (XOR-swizzled).
// S-frag (from mfma(Q,K)): q = g*4+r, k = jf*16+fr. Online softmax in-register.
// P round-trips through wave-private swizzled LDS to reach A-operand layout.
__global__ __launch_bounds__(256) void fattn_kernel(
    const __bf16* __restrict__ qkv, __bf16* __restrict__ y)
{
    const int bq = blockIdx.x, h = blockIdx.y, b = blockIdx.z;
    const int tid = threadIdx.x, lane = tid & 63, w = tid >> 6;
    const int fr = lane & 15, g = lane >> 4;

    __shared__ __align__(16) __bf16 Ks[64 * 64];
    __shared__ __align__(16) __bf16 Vt[64 * 64];
    __shared__ __align__(16) __bf16 Ps[4][16 * 64];

    const __bf16* base = qkv + (size_t)b * TDIM * E3;
    const int q0w = bq * 64 + w * 16;

    // Q fragments (A operand), hoisted: lane holds Q[q0w+fr][g*8..], [32+g*8..]
    bf16x8 qf[2];
    {
        const __bf16* qp = base + (size_t)(q0w + fr) * E3 + h * 64 + g * 8;
        qf[0] = *(const bf16x8*)qp;
        qf[1] = *(const bf16x8*)(qp + 32);
    }

    float m[4] = {-1e30f, -1e30f, -1e30f, -1e30f};
    float l[4] = {0.f, 0.f, 0.f, 0.f};
    f32x4 acc[4];
    #pragma unroll
    for (int jd = 0; jd < 4; ++jd) acc[jd] = (f32x4){0.f, 0.f, 0.f, 0.f};

    for (int kt = 0; kt <= bq; ++kt) {
        const int k0 = kt * 64;
        // ---- stage K (row-major swizzled) and V^T (swizzled) ----
        #pragma unroll
        for (int it = 0; it < 2; ++it) {
            const int s = tid + it * 256;
            const int row = s >> 3, ch = s & 7;   // K/V row (k), 16B chunk (d)
            const __bf16* gp = base + (size_t)(k0 + row) * E3 + EDIM + h * 64 + ch * 8;
            bf16x8 kv = *(const bf16x8*)gp;
            *(bf16x8*)(Ks + row * 64 + ((ch ^ (row & 7)) << 3)) = kv;
            bf16x8 vv = *(const bf16x8*)(gp + EDIM);
            #pragma unroll
            for (int j = 0; j < 8; ++j) {
                const int d = ch * 8 + j;
                const int key = ((d >> 3) ^ d) & 7;
                Vt[d * 64 + ((((row >> 3) ^ key) << 3) + (row & 7))] = vv[j];
            }
        }
        __syncthreads();

        // ---- QK^T: S[16 q][64 k] ----
        f32x4 s[4];
        #pragma unroll
        for (int jf = 0; jf < 4; ++jf) {
            const int krow = jf * 16 + fr;
            f32x4 sv = (f32x4){0.f, 0.f, 0.f, 0.f};
            #pragma unroll
            for (int kc = 0; kc < 2; ++kc) {
                bf16x8 kf = *(const bf16x8*)(Ks + krow * 64 + (((kc * 4 + g) ^ (fr & 7)) << 3));
                sv = __builtin_amdgcn_mfma_f32_16x16x32_bf16(qf[kc], kf, sv, 0, 0, 0);
            }
            s[jf] = sv;
        }
        // scale + causal mask (diagonal tile only)
        #pragma unroll
        for (int jf = 0; jf < 4; ++jf)
            #pragma unroll
            for (int r = 0; r < 4; ++r) s[jf][r] *= 0.125f;
        if (kt == bq) {
            #pragma unroll
            for (int jf = 0; jf < 4; ++jf) {
                const int k = k0 + jf * 16 + fr;
                #pragma unroll
                for (int r = 0; r < 4; ++r) {
                    const int q = q0w + g * 4 + r;
                    if (k > q) s[jf][r] = -1e30f;
                }
            }
        }

        // ---- online softmax (rows = (g,r); reduce over 16 lanes of group g) ----
        #pragma unroll
        for (int r = 0; r < 4; ++r) {
            float mx = fmaxf(fmaxf(s[0][r], s[1][r]), fmaxf(s[2][r], s[3][r]));
            mx = fmaxf(mx, __shfl_xor(mx, 1));
            mx = fmaxf(mx, __shfl_xor(mx, 2));
            mx = fmaxf(mx, __shfl_xor(mx, 4));
            mx = fmaxf(mx, __shfl_xor(mx, 8));
            const float mn = fmaxf(m[r], mx);
            const float sc2 = __expf(m[r] - mn);
            m[r] = mn;
            float rs = 0.f;
            #pragma unroll
            for (int jf = 0; jf < 4; ++jf) {
                const float p = __expf(s[jf][r] - mn);
                s[jf][r] = p;
                rs += p;
            }
            rs += __shfl_xor(rs, 1);
            rs += __shfl_xor(rs, 2);
            rs += __shfl_xor(rs, 4);
            rs += __shfl_xor(rs, 8);
            l[r] = l[r] * sc2 + rs;
            #pragma unroll
            for (int jd = 0; jd < 4; ++jd) acc[jd][r] *= sc2;
        }

        // ---- P -> wave-private LDS (swizzled), read back in A-operand layout ----
        __bf16* pw = &Ps[w][0];
        #pragma unroll
        for (int jf = 0; jf < 4; ++jf) {
            const int ch = jf * 2 + (fr >> 3);
            #pragma unroll
            for (int r = 0; r < 4; ++r) {
                const int row = g * 4 + r;
                pw[row * 64 + (((ch ^ (row & 7)) << 3) + (fr & 7))] = (__bf16)s[jf][r];
            }
        }
        asm volatile("s_waitcnt lgkmcnt(0)" ::: "memory");
        bf16x8 pa[2];
        #pragma unroll
        for (int kc = 0; kc < 2; ++kc)
            pa[kc] = *(const bf16x8*)(pw + fr * 64 + (((kc * 4 + g) ^ (fr & 7)) << 3));

        // ---- PV: O[16 q][64 d] += P @ V ----
        #pragma unroll
        for (int jd = 0; jd < 4; ++jd) {
            const int d = jd * 16 + fr;
            const int key = ((d >> 3) ^ d) & 7;
            #pragma unroll
            for (int kc = 0; kc < 2; ++kc) {
                bf16x8 vf = *(const bf16x8*)(Vt + d * 64 + (((kc * 4 + g) ^ key) << 3));
                acc[jd] = __builtin_amdgcn_mfma_f32_16x16x32_bf16(pa[kc], vf, acc[jd], 0, 0, 0);
            }
        }
        __syncthreads();
    }

    // ---- epilogue: y[q][h*64+d] = acc/l ----
    #pragma unroll
    for (int r = 0; r < 4; ++r) {
        const float inv = 1.0f / l[r];
        const int q = q0w + g * 4 + r;
        __bf16* yp = y + ((size_t)(b * TDIM + q)) * EDIM + h * 64;
        #pragma unroll
        for (int jd = 0; jd < 4; ++jd)
            yp[jd * 16 + fr] = (__bf16)(acc[jd][r] * inv);
    }
}

// ---------------------------------------------------------------- loss
__global__ __launch_bounds__(256) void nll_kernel(
    const float* __restrict__ logits, const int* __restrict__ targets,
    float* __restrict__ rr)
{
    const int row = blockIdx.x, tid = threadIdx.x;
    const float* lr = logits + (size_t)row * VDIM;
    float ml = -1e30f, sl = 0.f;
    for (int v = tid; v < VDIM; v += 256) {
        float xv = lr[v];
        if (xv > ml) { sl = sl * __expf(ml - xv) + 1.0f; ml = xv; }
        else sl += __expf(xv - ml);
    }
    #pragma unroll
    for (int off = 32; off; off >>= 1) {
        float om = __shfl_xor(ml, off), os = __shfl_xor(sl, off);
        if (om > ml) { sl = sl * __expf(ml - om) + os; ml = om; }
        else sl += os * __expf(om - ml);
    }
    __shared__ float rm[4], rs[4];
    const int lane = tid & 63, wid = tid >> 6;
    if (lane == 0) { rm[wid] = ml; rs[wid] = sl; }
    __syncthreads();
    if (tid == 0) {
        float M = rm[0], S = rs[0];
        for (int i = 1; i < 4; i++) {
            float om = rm[i], os = rs[i];
            if (om > M) { S = S * __expf(M - om) + os; M = om; }
            else S += os * __expf(om - M);
        }
        rr[row] = -(lr[targets[row]] - M - logf(S));
    }
}

__global__ __launch_bounds__(256) void loss_reduce_kernel(
    const float* __restrict__ rr, float* __restrict__ out)
{
    const int tid = threadIdx.x;
    float s = 0.f;
    for (int i = tid; i < BT; i += 256) s += rr[i];
    #pragma unroll
    for (int off = 32; off; off >>= 1) s += __shfl_xor(s, off);
    __shared__ float red[4];
    if ((tid & 63) == 0) red[tid >> 6] = s;
    __syncthreads();
    if (tid == 0) out[0] = (red[0] + red[1] + red[2] + red[3]) * (1.0f / BT);
}

// ---------------------------------------------------------------- launch
extern "C" void kernel_launch(void* const* d_in, const int* in_sizes, int n_in,
                              void* d_out, int out_size, void* d_ws, size_t ws_size,
                              hipStream_t stream)
{
    const int*   idx     = (const int*)d_in[0];
    const int*   targets = (const int*)d_in[1];
    const float* wte     = (const float*)d_in[2];
    const float* wpe     = (const float*)d_in[3];
    const float* ln1_w   = (const float*)d_in[4];
    const float* ln1_b   = (const float*)d_in[5];
    const float* attn_w  = (const float*)d_in[6];
    const float* attn_b  = (const float*)d_in[7];
    const float* proj_w  = (const float*)d_in[8];
    const float* proj_b  = (const float*)d_in[9];
    const float* ln2_w   = (const float*)d_in[10];
    const float* ln2_b   = (const float*)d_in[11];
    const float* fc_w    = (const float*)d_in[12];
    const float* fc_b    = (const float*)d_in[13];
    const float* fcp_w   = (const float*)d_in[14];
    const float* fcp_b   = (const float*)d_in[15];
    const float* lnf_w   = (const float*)d_in[16];
    const float* lnf_b   = (const float*)d_in[17];

    float* logits = (float*)d_out;

    char* wp = (char*)d_ws;
    float*  x     = (float*)wp;   wp += (size_t)BT * EDIM * 4;
    __bf16* qkvb  = (__bf16*)wp;  wp += (size_t)BT * E3 * 2;
    __bf16* xnbf  = (__bf16*)wp;  wp += (size_t)BT * EDIM * 2;
    __bf16* ybf   = (__bf16*)wp;  wp += (size_t)BT * EDIM * 2;
    __bf16* hbf   = (__bf16*)wp;  wp += (size_t)BT * E4 * 2;
    __bf16* wqkvb = (__bf16*)wp;  wp += (size_t)EDIM * E3 * 2;
    __bf16* wprjb = (__bf16*)wp;  wp += (size_t)EDIM * EDIM * 2;
    __bf16* wfcb  = (__bf16*)wp;  wp += (size_t)EDIM * E4 * 2;
    __bf16* wfpb  = (__bf16*)wp;  wp += (size_t)E4 * EDIM * 2;
    __bf16* wteb  = (__bf16*)wp;  wp += (size_t)VDIM * EDIM * 2;
    float*  rr    = (float*)wp;

    embed_kernel<<<BT, 256, 0, stream>>>(idx, wte, wpe, x);
    cvt_kernel<<<2048, 256, 0, stream>>>(wte, wteb, (long)VDIM * EDIM / 4);

    for (int l = 0; l < LNUM; ++l) {
        ln_kernel<<<BT, 256, 0, stream>>>(x, ln1_w + (size_t)l * EDIM,
                                          ln1_b + (size_t)l * EDIM, xnbf);
        convt_kernel<<<dim3(E3 / 32, EDIM / 32), 256, 0, stream>>>(
            attn_w + (size_t)l * EDIM * E3, wqkvb, EDIM, E3);
        mgemm<true, false, false, true, false><<<dim3(E3 / 128, BT / 128), 256, 0, stream>>>(
            xnbf, wqkvb, attn_b + (size_t)l * E3, nullptr, qkvb, BT, E3, EDIM);
        fattn_kernel<<<dim3(TDIM / 64, HNUM, BDIM), 256, 0, stream>>>(qkvb, ybf);
        convt_kernel<<<dim3(EDIM / 32, EDIM / 32), 256, 0, stream>>>(
            proj_w + (size_t)l * EDIM * EDIM, wprjb, EDIM, EDIM);
        mgemm<true, false, true, false, false><<<dim3(EDIM / 128, BT / 128), 256, 0, stream>>>(
            ybf, wprjb, proj_b + (size_t)l * EDIM, x, x, BT, EDIM, EDIM);
        ln_kernel<<<BT, 256, 0, stream>>>(x, ln2_w + (size_t)l * EDIM,
                                          ln2_b + (size_t)l * EDIM, xnbf);
        convt_kernel<<<dim3(E4 / 32, EDIM / 32), 256, 0, stream>>>(
            fc_w + (size_t)l * EDIM * E4, wfcb, EDIM, E4);
        mgemm<true, true, false, true, false><<<dim3(E4 / 128, BT / 128), 256, 0, stream>>>(
            xnbf, wfcb, fc_b + (size_t)l * E4, nullptr, hbf, BT, E4, EDIM);
        convt_kernel<<<dim3(EDIM / 32, E4 / 32), 256, 0, stream>>>(
            fcp_w + (size_t)l * E4 * EDIM, wfpb, E4, EDIM);
        mgemm<true, false, true, false, false><<<dim3(EDIM / 128, BT / 128), 256, 0, stream>>>(
            hbf, wfpb, fcp_b + (size_t)l * EDIM, x, x, BT, EDIM, E4);
    }

    ln_kernel<<<BT, 256, 0, stream>>>(x, lnf_w, lnf_b, xnbf);
    mgemm<false, false, false, false, true><<<dim3((VDIM + 127) / 128, BT / 128), 256, 0, stream>>>(
        xnbf, wteb, nullptr, nullptr, logits, BT, VDIM, EDIM);
    nll_kernel<<<BT, 256, 0, stream>>>(logits, targets, rr);
    loss_reduce_kernel<<<1, 256, 0, stream>>>(rr, logits + (size_t)BT * VDIM);
}

// Round 4
// 2827.492 us; speedup vs baseline: 9.3037x; 1.0501x over previous
//
#include <hip/hip_runtime.h>
#include <hip/hip_bf16.h>
#include <math.h>

#define LNUM 12
#define HNUM 12
#define EDIM 768
#define VDIM 50257
#define BDIM 2
#define TDIM 1024
#define BT (BDIM*TDIM)
#define E3 (3*EDIM)
#define E4 (4*EDIM)
#define NPB (2*((VDIM+127)/128))   // 786 half-tile partials per row

typedef __bf16 bf16x8 __attribute__((ext_vector_type(8)));
typedef float f32x4 __attribute__((ext_vector_type(4)));

__device__ __forceinline__ float gelu_f(float x) {
    float u = 0.7978845608028654f * (x + 0.044715f * x * x * x);
    return 0.5f * x * (1.0f + tanhf(u));
}

// async global->LDS, 16B per lane
__device__ __forceinline__ void gl16(const void* g, void* l) {
    __builtin_amdgcn_global_load_lds(
        (const __attribute__((address_space(1))) unsigned int*)g,
        (__attribute__((address_space(3))) unsigned int*)l,
        16, 0, 0);
}

// ---------------------------------------------------------------- embedding
__global__ __launch_bounds__(256) void embed_kernel(
    const int* __restrict__ idx, const float* __restrict__ wte,
    const float* __restrict__ wpe, float* __restrict__ x)
{
    const int row = blockIdx.x;
    const int t = row % TDIM;
    const int tok = idx[row];
    const float* we = wte + (size_t)tok * EDIM;
    const float* pe = wpe + (size_t)t * EDIM;
    float* xr = x + (size_t)row * EDIM;
    for (int e = threadIdx.x; e < EDIM; e += 256) xr[e] = we[e] + pe[e];
}

// ---------------------------------------------------------------- layernorm (bf16 out)
__global__ __launch_bounds__(256) void ln_kernel(
    const float* __restrict__ in, const float* __restrict__ w,
    const float* __restrict__ b, __bf16* __restrict__ out)
{
    const int row = blockIdx.x, tid = threadIdx.x;
    const float* xr = in + (size_t)row * EDIM;
    float v0 = xr[tid], v1 = xr[tid + 256], v2 = xr[tid + 512];
    float s = v0 + v1 + v2;
    __shared__ float red[8];
    const int lane = tid & 63, wid = tid >> 6;
    #pragma unroll
    for (int off = 32; off; off >>= 1) s += __shfl_xor(s, off);
    if (lane == 0) red[wid] = s;
    __syncthreads();
    const float mean = (red[0] + red[1] + red[2] + red[3]) * (1.0f / EDIM);
    float d0 = v0 - mean, d1 = v1 - mean, d2 = v2 - mean;
    float s2 = d0 * d0 + d1 * d1 + d2 * d2;
    #pragma unroll
    for (int off = 32; off; off >>= 1) s2 += __shfl_xor(s2, off);
    if (lane == 0) red[4 + wid] = s2;
    __syncthreads();
    const float var = (red[4] + red[5] + red[6] + red[7]) * (1.0f / EDIM);
    const float inv = rsqrtf(var + 1e-5f);
    __bf16* orow = out + (size_t)row * EDIM;
    orow[tid]       = (__bf16)(d0 * inv * w[tid]       + b[tid]);
    orow[tid + 256] = (__bf16)(d1 * inv * w[tid + 256] + b[tid + 256]);
    orow[tid + 512] = (__bf16)(d2 * inv * w[tid + 512] + b[tid + 512]);
}

// ------------------------------------------------- weight convert: f32 [K][N] -> bf16 [N][K]
// blockIdx.z = layer (in/out strided by K*N per layer)
__global__ __launch_bounds__(256) void convt_kernel(
    const float* __restrict__ in, __bf16* __restrict__ out, int K, int N)
{
    in  += (size_t)blockIdx.z * K * N;
    out += (size_t)blockIdx.z * K * N;
    __shared__ float t[32][33];
    const int n0 = blockIdx.x * 32, k0 = blockIdx.y * 32;
    const int tx = threadIdx.x & 31, ty = threadIdx.x >> 5;
    #pragma unroll
    for (int r = ty; r < 32; r += 8)
        t[r][tx] = in[(size_t)(k0 + r) * N + n0 + tx];
    __syncthreads();
    #pragma unroll
    for (int r = ty; r < 32; r += 8)
        out[(size_t)(n0 + r) * K + k0 + tx] = (__bf16)t[tx][r];
}

// ------------------------------------------------- elementwise f32 -> bf16 (wte)
__global__ __launch_bounds__(256) void cvt_kernel(
    const float* __restrict__ in, __bf16* __restrict__ out, long n4)
{
    for (long i = blockIdx.x * 256L + threadIdx.x; i < n4; i += (long)gridDim.x * 256L) {
        float4 v = ((const float4*)in)[i];
        out[i * 4 + 0] = (__bf16)v.x;
        out[i * 4 + 1] = (__bf16)v.y;
        out[i * 4 + 2] = (__bf16)v.z;
        out[i * 4 + 3] = (__bf16)v.w;
    }
}

// ---------------------------------------------------------------- MFMA GEMM
// C[M,N] = act(A[M,K] @ Bt[N,K]^T + bias) (+res). A,Bt bf16 row-major (k-contiguous).
// LOGITS: grid is (M/128, N-tiles) [flipped for B-panel L2 reuse], writes f32 C
// plus per-(row, 64-col half-tile) sum(exp(v)) partials for fused log-softmax.
template<bool BIAS, bool GELU_, bool RES_, bool OUTBF, bool NGUARD, bool LOGITS>
__global__ __launch_bounds__(256) void mgemm(
    const __bf16* __restrict__ A, const __bf16* __restrict__ Bt,
    const float* __restrict__ bias, const float* __restrict__ res,
    void* __restrict__ Cout, float* __restrict__ part, int M, int N, int K)
{
    __shared__ __align__(16) __bf16 As[4096];   // 128 rows x 32 k
    __shared__ __align__(16) __bf16 Bs[4096];
    const int tid = threadIdx.x;
    const int lane = tid & 63;
    const int wave = tid >> 6;
    const int wr = wave >> 1, wc = wave & 1;
    const int bm = LOGITS ? blockIdx.x : blockIdx.y;
    const int bn = LOGITS ? blockIdx.y : blockIdx.x;
    const int m0 = bm * 128;
    const int n0 = bn * 128;

    const int srow = tid >> 2;
    const int c0 = (tid & 3) ^ ((srow >> 1) & 3);

    const __bf16* ga0 = A + (size_t)(m0 + srow) * K + c0 * 8;
    const __bf16* ga1 = ga0 + (size_t)64 * K;
    int nr0 = n0 + srow, nr1 = n0 + srow + 64;
    if (NGUARD) { nr0 = nr0 < N ? nr0 : N - 1; nr1 = nr1 < N ? nr1 : N - 1; }
    const __bf16* gb0 = Bt + (size_t)nr0 * K + c0 * 8;
    const __bf16* gb1 = Bt + (size_t)nr1 * K + c0 * 8;

    char* const lA0 = (char*)As + tid * 16;
    char* const lA1 = (char*)As + 4096 + tid * 16;
    char* const lB0 = (char*)Bs + tid * 16;
    char* const lB1 = (char*)Bs + 4096 + tid * 16;

    const int fr = lane & 15;
    const int g = lane >> 4;
    const int slot = ((g ^ ((lane >> 1) & 3)) << 4);
    const int offA = (wr * 64 + fr) * 64 + slot;
    const int offB = (wc * 64 + fr) * 64 + slot;

    f32x4 acc[4][4];
    #pragma unroll
    for (int i = 0; i < 4; i++)
        #pragma unroll
        for (int j = 0; j < 4; j++) acc[i][j] = (f32x4){0.f, 0.f, 0.f, 0.f};

    for (int k0 = 0; k0 < K; k0 += 32) {
        gl16(ga0 + k0, lA0);
        gl16(ga1 + k0, lA1);
        gl16(gb0 + k0, lB0);
        gl16(gb1 + k0, lB1);
        __syncthreads();
        bf16x8 af[4], bfr[4];
        #pragma unroll
        for (int i = 0; i < 4; i++)
            af[i] = *(const bf16x8*)((const char*)As + offA + i * 1024);
        #pragma unroll
        for (int j = 0; j < 4; j++)
            bfr[j] = *(const bf16x8*)((const char*)Bs + offB + j * 1024);
        #pragma unroll
        for (int i = 0; i < 4; i++)
            #pragma unroll
            for (int j = 0; j < 4; j++)
                acc[i][j] = __builtin_amdgcn_mfma_f32_16x16x32_bf16(af[i], bfr[j], acc[i][j], 0, 0, 0);
        __syncthreads();
    }

    const int crow = g * 4;
    if (LOGITS) {
        const int bn2 = bn * 2 + wc;
        #pragma unroll
        for (int i = 0; i < 4; i++) {
            #pragma unroll
            for (int r = 0; r < 4; r++) {
                const int m = m0 + wr * 64 + i * 16 + crow + r;
                float se = 0.f;
                #pragma unroll
                for (int j = 0; j < 4; j++) {
                    const int n = n0 + wc * 64 + j * 16 + fr;
                    if (!NGUARD || n < N) {
                        float v = acc[i][j][r];
                        ((float*)Cout)[(size_t)m * N + n] = v;
                        se += __expf(v);
                    }
                }
                se += __shfl_xor(se, 1); se += __shfl_xor(se, 2);
                se += __shfl_xor(se, 4); se += __shfl_xor(se, 8);
                if (fr == 0) part[(size_t)m * NPB + bn2] = se;
            }
        }
    } else {
        #pragma unroll
        for (int i = 0; i < 4; i++) {
            #pragma unroll
            for (int r = 0; r < 4; r++) {
                const int m = m0 + wr * 64 + i * 16 + crow + r;
                #pragma unroll
                for (int j = 0; j < 4; j++) {
                    const int n = n0 + wc * 64 + j * 16 + fr;
                    if (!NGUARD || n < N) {
                        float v = acc[i][j][r];
                        if (BIAS) v += bias[n];
                        if (GELU_) v = gelu_f(v);
                        if (RES_) v += res[(size_t)m * N + n];
                        if (OUTBF) ((__bf16*)Cout)[(size_t)m * N + n] = (__bf16)v;
                        else       ((float*)Cout)[(size_t)m * N + n] = v;
                    }
                }
            }
        }
    }
}

// ---------------------------------------------------------------- flash attention (bf16 MFMA)
__global__ __launch_bounds__(256) void fattn_kernel(
    const __bf16* __restrict__ qkv, __bf16* __restrict__ y)
{
    const int bq = blockIdx.x, h = blockIdx.y, b = blockIdx.z;
    const int tid = threadIdx.x, lane = tid & 63, w = tid >> 6;
    const int fr = lane & 15, g = lane >> 4;

    __shared__ __align__(16) __bf16 Ks[64 * 64];
    __shared__ __align__(16) __bf16 Vt[64 * 64];
    __shared__ __align__(16) __bf16 Ps[4][16 * 64];

    const __bf16* base = qkv + (size_t)b * TDIM * E3;
    const int q0w = bq * 64 + w * 16;

    bf16x8 qf[2];
    {
        const __bf16* qp = base + (size_t)(q0w + fr) * E3 + h * 64 + g * 8;
        qf[0] = *(const bf16x8*)qp;
        qf[1] = *(const bf16x8*)(qp + 32);
    }

    float m[4] = {-1e30f, -1e30f, -1e30f, -1e30f};
    float l[4] = {0.f, 0.f, 0.f, 0.f};
    f32x4 acc[4];
    #pragma unroll
    for (int jd = 0; jd < 4; ++jd) acc[jd] = (f32x4){0.f, 0.f, 0.f, 0.f};

    for (int kt = 0; kt <= bq; ++kt) {
        const int k0 = kt * 64;
        #pragma unroll
        for (int it = 0; it < 2; ++it) {
            const int s = tid + it * 256;
            const int row = s >> 3, ch = s & 7;
            const __bf16* gp = base + (size_t)(k0 + row) * E3 + EDIM + h * 64 + ch * 8;
            bf16x8 kv = *(const bf16x8*)gp;
            *(bf16x8*)(Ks + row * 64 + ((ch ^ (row & 7)) << 3)) = kv;
            bf16x8 vv = *(const bf16x8*)(gp + EDIM);
            #pragma unroll
            for (int j = 0; j < 8; ++j) {
                const int d = ch * 8 + j;
                const int key = ((d >> 3) ^ d) & 7;
                Vt[d * 64 + ((((row >> 3) ^ key) << 3) + (row & 7))] = vv[j];
            }
        }
        __syncthreads();

        f32x4 s[4];
        #pragma unroll
        for (int jf = 0; jf < 4; ++jf) {
            const int krow = jf * 16 + fr;
            f32x4 sv = (f32x4){0.f, 0.f, 0.f, 0.f};
            #pragma unroll
            for (int kc = 0; kc < 2; ++kc) {
                bf16x8 kf = *(const bf16x8*)(Ks + krow * 64 + (((kc * 4 + g) ^ (fr & 7)) << 3));
                sv = __builtin_amdgcn_mfma_f32_16x16x32_bf16(qf[kc], kf, sv, 0, 0, 0);
            }
            s[jf] = sv;
        }
        #pragma unroll
        for (int jf = 0; jf < 4; ++jf)
            #pragma unroll
            for (int r = 0; r < 4; ++r) s[jf][r] *= 0.125f;
        if (kt == bq) {
            #pragma unroll
            for (int jf = 0; jf < 4; ++jf) {
                const int k = k0 + jf * 16 + fr;
                #pragma unroll
                for (int r = 0; r < 4; ++r) {
                    const int q = q0w + g * 4 + r;
                    if (k > q) s[jf][r] = -1e30f;
                }
            }
        }

        #pragma unroll
        for (int r = 0; r < 4; ++r) {
            float mx = fmaxf(fmaxf(s[0][r], s[1][r]), fmaxf(s[2][r], s[3][r]));
            mx = fmaxf(mx, __shfl_xor(mx, 1));
            mx = fmaxf(mx, __shfl_xor(mx, 2));
            mx = fmaxf(mx, __shfl_xor(mx, 4));
            mx = fmaxf(mx, __shfl_xor(mx, 8));
            const float mn = fmaxf(m[r], mx);
            const float sc2 = __expf(m[r] - mn);
            m[r] = mn;
            float rs = 0.f;
            #pragma unroll
            for (int jf = 0; jf < 4; ++jf) {
                const float p = __expf(s[jf][r] - mn);
                s[jf][r] = p;
                rs += p;
            }
            rs += __shfl_xor(rs, 1);
            rs += __shfl_xor(rs, 2);
            rs += __shfl_xor(rs, 4);
            rs += __shfl_xor(rs, 8);
            l[r] = l[r] * sc2 + rs;
            #pragma unroll
            for (int jd = 0; jd < 4; ++jd) acc[jd][r] *= sc2;
        }

        __bf16* pw = &Ps[w][0];
        #pragma unroll
        for (int jf = 0; jf < 4; ++jf) {
            const int ch = jf * 2 + (fr >> 3);
            #pragma unroll
            for (int r = 0; r < 4; ++r) {
                const int row = g * 4 + r;
                pw[row * 64 + (((ch ^ (row & 7)) << 3) + (fr & 7))] = (__bf16)s[jf][r];
            }
        }
        asm volatile("s_waitcnt lgkmcnt(0)" ::: "memory");
        bf16x8 pa[2];
        #pragma unroll
        for (int kc = 0; kc < 2; ++kc)
            pa[kc] = *(const bf16x8*)(pw + fr * 64 + (((kc * 4 + g) ^ (fr & 7)) << 3));

        #pragma unroll
        for (int jd = 0; jd < 4; ++jd) {
            const int d = jd * 16 + fr;
            const int key = ((d >> 3) ^ d) & 7;
            #pragma unroll
            for (int kc = 0; kc < 2; ++kc) {
                bf16x8 vf = *(const bf16x8*)(Vt + d * 64 + (((kc * 4 + g) ^ key) << 3));
                acc[jd] = __builtin_amdgcn_mfma_f32_16x16x32_bf16(pa[kc], vf, acc[jd], 0, 0, 0);
            }
        }
        __syncthreads();
    }

    #pragma unroll
    for (int r = 0; r < 4; ++r) {
        const float inv = 1.0f / l[r];
        const int q = q0w + g * 4 + r;
        __bf16* yp = y + ((size_t)(b * TDIM + q)) * EDIM + h * 64;
        #pragma unroll
        for (int jd = 0; jd < 4; ++jd)
            yp[jd * 16 + fr] = (__bf16)(acc[jd][r] * inv);
    }
}

// ---------------------------------------------------------------- fused-LSE finalize
__global__ __launch_bounds__(256) void lsefin_kernel(
    const float* __restrict__ part, const float* __restrict__ logits,
    const int* __restrict__ targets, float* __restrict__ rr)
{
    const int row = blockIdx.x, tid = threadIdx.x;
    float s = 0.f;
    for (int j = tid; j < NPB; j += 256) s += part[(size_t)row * NPB + j];
    #pragma unroll
    for (int off = 32; off; off >>= 1) s += __shfl_xor(s, off);
    __shared__ float red[4];
    if ((tid & 63) == 0) red[tid >> 6] = s;
    __syncthreads();
    if (tid == 0) {
        float S = red[0] + red[1] + red[2] + red[3];
        rr[row] = logf(S) - logits[(size_t)row * VDIM + targets[row]];
    }
}

__global__ __launch_bounds__(256) void loss_reduce_kernel(
    const float* __restrict__ rr, float* __restrict__ out)
{
    const int tid = threadIdx.x;
    float s = 0.f;
    for (int i = tid; i < BT; i += 256) s += rr[i];
    #pragma unroll
    for (int off = 32; off; off >>= 1) s += __shfl_xor(s, off);
    __shared__ float red[4];
    if ((tid & 63) == 0) red[tid >> 6] = s;
    __syncthreads();
    if (tid == 0) out[0] = (red[0] + red[1] + red[2] + red[3]) * (1.0f / BT);
}

// ---------------------------------------------------------------- launch
extern "C" void kernel_launch(void* const* d_in, const int* in_sizes, int n_in,
                              void* d_out, int out_size, void* d_ws, size_t ws_size,
                              hipStream_t stream)
{
    const int*   idx     = (const int*)d_in[0];
    const int*   targets = (const int*)d_in[1];
    const float* wte     = (const float*)d_in[2];
    const float* wpe     = (const float*)d_in[3];
    const float* ln1_w   = (const float*)d_in[4];
    const float* ln1_b   = (const float*)d_in[5];
    const float* attn_w  = (const float*)d_in[6];
    const float* attn_b  = (const float*)d_in[7];
    const float* proj_w  = (const float*)d_in[8];
    const float* proj_b  = (const float*)d_in[9];
    const float* ln2_w   = (const float*)d_in[10];
    const float* ln2_b   = (const float*)d_in[11];
    const float* fc_w    = (const float*)d_in[12];
    const float* fc_b    = (const float*)d_in[13];
    const float* fcp_w   = (const float*)d_in[14];
    const float* fcp_b   = (const float*)d_in[15];
    const float* lnf_w   = (const float*)d_in[16];
    const float* lnf_b   = (const float*)d_in[17];

    float* logits = (float*)d_out;

    const size_t slq = (size_t)EDIM * E3, slp = (size_t)EDIM * EDIM;
    const size_t slf = (size_t)EDIM * E4, slfp = (size_t)E4 * EDIM;

    char* wp = (char*)d_ws;
    float*  x     = (float*)wp;   wp += (size_t)BT * EDIM * 4;
    __bf16* qkvb  = (__bf16*)wp;  wp += (size_t)BT * E3 * 2;
    __bf16* xnbf  = (__bf16*)wp;  wp += (size_t)BT * EDIM * 2;
    __bf16* ybf   = (__bf16*)wp;  wp += (size_t)BT * EDIM * 2;
    __bf16* hbf   = (__bf16*)wp;  wp += (size_t)BT * E4 * 2;
    __bf16* wteb  = (__bf16*)wp;  wp += (size_t)VDIM * EDIM * 2;
    float*  part  = (float*)wp;   wp += (size_t)BT * NPB * 4;
    float*  rr    = (float*)wp;   wp += (size_t)BT * 4;
    __bf16* wqkvb = (__bf16*)wp;

    // big path: all layers' weights converted upfront; small path: per-layer reuse
    const size_t wbytes_all = (slq + slp + slf + slfp) * 2 * LNUM;
    const size_t used = (size_t)(wp - (char*)d_ws);
    const bool big = ws_size >= used + wbytes_all;
    const size_t L = big ? LNUM : 1;
    __bf16* wprjb = wqkvb + slq * L;
    __bf16* wfcb  = wprjb + slp * L;
    __bf16* wfpb  = wfcb  + slf * L;

    embed_kernel<<<BT, 256, 0, stream>>>(idx, wte, wpe, x);
    cvt_kernel<<<2048, 256, 0, stream>>>(wte, wteb, (long)VDIM * EDIM / 4);

    if (big) {
        convt_kernel<<<dim3(E3 / 32, EDIM / 32, LNUM), 256, 0, stream>>>(attn_w, wqkvb, EDIM, E3);
        convt_kernel<<<dim3(EDIM / 32, EDIM / 32, LNUM), 256, 0, stream>>>(proj_w, wprjb, EDIM, EDIM);
        convt_kernel<<<dim3(E4 / 32, EDIM / 32, LNUM), 256, 0, stream>>>(fc_w, wfcb, EDIM, E4);
        convt_kernel<<<dim3(EDIM / 32, E4 / 32, LNUM), 256, 0, stream>>>(fcp_w, wfpb, E4, EDIM);
    }

    for (int l = 0; l < LNUM; ++l) {
        const __bf16* wq = wqkvb + (big ? (size_t)l * slq : 0);
        const __bf16* wpj = wprjb + (big ? (size_t)l * slp : 0);
        const __bf16* wf = wfcb + (big ? (size_t)l * slf : 0);
        const __bf16* wfp = wfpb + (big ? (size_t)l * slfp : 0);

        ln_kernel<<<BT, 256, 0, stream>>>(x, ln1_w + (size_t)l * EDIM,
                                          ln1_b + (size_t)l * EDIM, xnbf);
        if (!big)
            convt_kernel<<<dim3(E3 / 32, EDIM / 32), 256, 0, stream>>>(
                attn_w + (size_t)l * slq, (__bf16*)wq, EDIM, E3);
        mgemm<true, false, false, true, false, false><<<dim3(E3 / 128, BT / 128), 256, 0, stream>>>(
            xnbf, wq, attn_b + (size_t)l * E3, nullptr, qkvb, nullptr, BT, E3, EDIM);
        fattn_kernel<<<dim3(TDIM / 64, HNUM, BDIM), 256, 0, stream>>>(qkvb, ybf);
        if (!big)
            convt_kernel<<<dim3(EDIM / 32, EDIM / 32), 256, 0, stream>>>(
                proj_w + (size_t)l * slp, (__bf16*)wpj, EDIM, EDIM);
        mgemm<true, false, true, false, false, false><<<dim3(EDIM / 128, BT / 128), 256, 0, stream>>>(
            ybf, wpj, proj_b + (size_t)l * EDIM, x, x, nullptr, BT, EDIM, EDIM);
        ln_kernel<<<BT, 256, 0, stream>>>(x, ln2_w + (size_t)l * EDIM,
                                          ln2_b + (size_t)l * EDIM, xnbf);
        if (!big)
            convt_kernel<<<dim3(E4 / 32, EDIM / 32), 256, 0, stream>>>(
                fc_w + (size_t)l * slf, (__bf16*)wf, EDIM, E4);
        mgemm<true, true, false, true, false, false><<<dim3(E4 / 128, BT / 128), 256, 0, stream>>>(
            xnbf, wf, fc_b + (size_t)l * E4, nullptr, hbf, nullptr, BT, E4, EDIM);
        if (!big)
            convt_kernel<<<dim3(EDIM / 32, E4 / 32), 256, 0, stream>>>(
                fcp_w + (size_t)l * slfp, (__bf16*)wfp, E4, EDIM);
        mgemm<true, false, true, false, false, false><<<dim3(EDIM / 128, BT / 128), 256, 0, stream>>>(
            hbf, wfp, fcp_b + (size_t)l * EDIM, x, x, nullptr, BT, EDIM, E4);
    }

    ln_kernel<<<BT, 256, 0, stream>>>(x, lnf_w, lnf_b, xnbf);
    // logits GEMM: grid flipped (M fast) for B-panel L2 reuse; fused sum-exp partials
    mgemm<false, false, false, false, true, true><<<dim3(BT / 128, (VDIM + 127) / 128), 256, 0, stream>>>(
        xnbf, wteb, nullptr, nullptr, logits, part, BT, VDIM, EDIM);
    lsefin_kernel<<<BT, 256, 0, stream>>>(part, logits, targets, rr);
    loss_reduce_kernel<<<1, 256, 0, stream>>>(rr, logits + (size_t)BT * VDIM);
}

// Round 5
// 2706.122 us; speedup vs baseline: 9.7209x; 1.0448x over previous
//
#include <hip/hip_runtime.h>
#include <hip/hip_bf16.h>
#include <math.h>

#define LNUM 12
#define HNUM 12
#define EDIM 768
#define VDIM 50257
#define BDIM 2
#define TDIM 1024
#define BT (BDIM*TDIM)
#define E3 (3*EDIM)
#define E4 (4*EDIM)
#define NPB (2*((VDIM+127)/128))   // 786 half-tile partials per row

typedef __bf16 bf16x8 __attribute__((ext_vector_type(8)));
typedef float f32x4 __attribute__((ext_vector_type(4)));

__device__ __forceinline__ float gelu_f(float x) {
    float u = 0.7978845608028654f * (x + 0.044715f * x * x * x);
    return 0.5f * x * (1.0f + tanhf(u));
}

// async global->LDS, 16B per lane
__device__ __forceinline__ void gl16(const void* g, void* l) {
    __builtin_amdgcn_global_load_lds(
        (const __attribute__((address_space(1))) unsigned int*)g,
        (__attribute__((address_space(3))) unsigned int*)l,
        16, 0, 0);
}

// ---------------------------------------------------------------- embedding
__global__ __launch_bounds__(256) void embed_kernel(
    const int* __restrict__ idx, const float* __restrict__ wte,
    const float* __restrict__ wpe, float* __restrict__ x)
{
    const int row = blockIdx.x;
    const int t = row % TDIM;
    const int tok = idx[row];
    const float* we = wte + (size_t)tok * EDIM;
    const float* pe = wpe + (size_t)t * EDIM;
    float* xr = x + (size_t)row * EDIM;
    for (int e = threadIdx.x; e < EDIM; e += 256) xr[e] = we[e] + pe[e];
}

// ---------------------------------------------------------------- layernorm (bf16 out)
__global__ __launch_bounds__(256) void ln_kernel(
    const float* __restrict__ in, const float* __restrict__ w,
    const float* __restrict__ b, __bf16* __restrict__ out)
{
    const int row = blockIdx.x, tid = threadIdx.x;
    const float* xr = in + (size_t)row * EDIM;
    float v0 = xr[tid], v1 = xr[tid + 256], v2 = xr[tid + 512];
    float s = v0 + v1 + v2;
    __shared__ float red[8];
    const int lane = tid & 63, wid = tid >> 6;
    #pragma unroll
    for (int off = 32; off; off >>= 1) s += __shfl_xor(s, off);
    if (lane == 0) red[wid] = s;
    __syncthreads();
    const float mean = (red[0] + red[1] + red[2] + red[3]) * (1.0f / EDIM);
    float d0 = v0 - mean, d1 = v1 - mean, d2 = v2 - mean;
    float s2 = d0 * d0 + d1 * d1 + d2 * d2;
    #pragma unroll
    for (int off = 32; off; off >>= 1) s2 += __shfl_xor(s2, off);
    if (lane == 0) red[4 + wid] = s2;
    __syncthreads();
    const float var = (red[4] + red[5] + red[6] + red[7]) * (1.0f / EDIM);
    const float inv = rsqrtf(var + 1e-5f);
    __bf16* orow = out + (size_t)row * EDIM;
    orow[tid]       = (__bf16)(d0 * inv * w[tid]       + b[tid]);
    orow[tid + 256] = (__bf16)(d1 * inv * w[tid + 256] + b[tid + 256]);
    orow[tid + 512] = (__bf16)(d2 * inv * w[tid + 512] + b[tid + 512]);
}

// ------------------------------------------------- weight convert: f32 [K][N] -> bf16 [N][K]
__global__ __launch_bounds__(256) void convt_kernel(
    const float* __restrict__ in, __bf16* __restrict__ out, int K, int N)
{
    in  += (size_t)blockIdx.z * K * N;
    out += (size_t)blockIdx.z * K * N;
    __shared__ float t[32][33];
    const int n0 = blockIdx.x * 32, k0 = blockIdx.y * 32;
    const int tx = threadIdx.x & 31, ty = threadIdx.x >> 5;
    #pragma unroll
    for (int r = ty; r < 32; r += 8)
        t[r][tx] = in[(size_t)(k0 + r) * N + n0 + tx];
    __syncthreads();
    #pragma unroll
    for (int r = ty; r < 32; r += 8)
        out[(size_t)(n0 + r) * K + k0 + tx] = (__bf16)t[tx][r];
}

// ------------------------------------------------- elementwise f32 -> bf16 (wte)
__global__ __launch_bounds__(256) void cvt_kernel(
    const float* __restrict__ in, __bf16* __restrict__ out, long n4)
{
    for (long i = blockIdx.x * 256L + threadIdx.x; i < n4; i += (long)gridDim.x * 256L) {
        float4 v = ((const float4*)in)[i];
        out[i * 4 + 0] = (__bf16)v.x;
        out[i * 4 + 1] = (__bf16)v.y;
        out[i * 4 + 2] = (__bf16)v.z;
        out[i * 4 + 3] = (__bf16)v.w;
    }
}

// ---------------------------------------------------------------- MFMA GEMM (2-phase dbuf)
// C[M,N] = act(A[M,K] @ Bt[N,K]^T + bias) (+res). A,Bt bf16 row-major (k-contiguous).
// 128x128 tile, BK=32, double-buffered LDS; next tile staged (global_load_lds)
// BEFORE current tile's ds_read+MFMA; ONE barrier per K-step (T3 minimum 2-phase).
template<bool BIAS, bool GELU_, bool RES_, bool OUTBF, bool NGUARD, bool LOGITS>
__global__ __launch_bounds__(256) void mgemm(
    const __bf16* __restrict__ A, const __bf16* __restrict__ Bt,
    const float* __restrict__ bias, const float* __restrict__ res,
    void* __restrict__ Cout, float* __restrict__ part, int M, int N, int K)
{
    __shared__ __align__(16) __bf16 As[2][4096];   // per buf: 128 rows x 32 k
    __shared__ __align__(16) __bf16 Bs[2][4096];
    const int tid = threadIdx.x;
    const int lane = tid & 63;
    const int wave = tid >> 6;
    const int wr = wave >> 1, wc = wave & 1;
    const int bm = LOGITS ? blockIdx.x : blockIdx.y;
    const int bn = LOGITS ? blockIdx.y : blockIdx.x;
    const int m0 = bm * 128;
    const int n0 = bn * 128;

    const int srow = tid >> 2;
    const int c0 = (tid & 3) ^ ((srow >> 1) & 3);

    const __bf16* ga0 = A + (size_t)(m0 + srow) * K + c0 * 8;
    const __bf16* ga1 = ga0 + (size_t)64 * K;
    int nr0 = n0 + srow, nr1 = n0 + srow + 64;
    if (NGUARD) { nr0 = nr0 < N ? nr0 : N - 1; nr1 = nr1 < N ? nr1 : N - 1; }
    const __bf16* gb0 = Bt + (size_t)nr0 * K + c0 * 8;
    const __bf16* gb1 = Bt + (size_t)nr1 * K + c0 * 8;

    const int fr = lane & 15;
    const int g = lane >> 4;
    const int slot = ((g ^ ((lane >> 1) & 3)) << 4);
    const int offA = (wr * 64 + fr) * 64 + slot;
    const int offB = (wc * 64 + fr) * 64 + slot;

    f32x4 acc[4][4];
    #pragma unroll
    for (int i = 0; i < 4; i++)
        #pragma unroll
        for (int j = 0; j < 4; j++) acc[i][j] = (f32x4){0.f, 0.f, 0.f, 0.f};

    const int nt = K >> 5;
    // prologue: stage tile 0 into buf 0
    gl16(ga0, (char*)As[0] + tid * 16);
    gl16(ga1, (char*)As[0] + 4096 + tid * 16);
    gl16(gb0, (char*)Bs[0] + tid * 16);
    gl16(gb1, (char*)Bs[0] + 4096 + tid * 16);
    __syncthreads();

    int buf = 0;
    for (int t = 0; t < nt; ++t) {
        if (t + 1 < nt) {   // stage next tile into other buffer (overlaps MFMA below)
            const int k1 = (t + 1) << 5;
            gl16(ga0 + k1, (char*)As[buf ^ 1] + tid * 16);
            gl16(ga1 + k1, (char*)As[buf ^ 1] + 4096 + tid * 16);
            gl16(gb0 + k1, (char*)Bs[buf ^ 1] + tid * 16);
            gl16(gb1 + k1, (char*)Bs[buf ^ 1] + 4096 + tid * 16);
        }
        const char* pa = (const char*)As[buf];
        const char* pb = (const char*)Bs[buf];
        bf16x8 af[4], bfr[4];
        #pragma unroll
        for (int i = 0; i < 4; i++)
            af[i] = *(const bf16x8*)(pa + offA + i * 1024);
        #pragma unroll
        for (int j = 0; j < 4; j++)
            bfr[j] = *(const bf16x8*)(pb + offB + j * 1024);
        #pragma unroll
        for (int i = 0; i < 4; i++)
            #pragma unroll
            for (int j = 0; j < 4; j++)
                acc[i][j] = __builtin_amdgcn_mfma_f32_16x16x32_bf16(af[i], bfr[j], acc[i][j], 0, 0, 0);
        __syncthreads();   // drains vmcnt (next tile) + lgkm; one barrier per K-step
        buf ^= 1;
    }

    const int crow = g * 4;
    if (LOGITS) {
        const int bn2 = bn * 2 + wc;
        #pragma unroll
        for (int i = 0; i < 4; i++) {
            #pragma unroll
            for (int r = 0; r < 4; r++) {
                const int m = m0 + wr * 64 + i * 16 + crow + r;
                float se = 0.f;
                #pragma unroll
                for (int j = 0; j < 4; j++) {
                    const int n = n0 + wc * 64 + j * 16 + fr;
                    if (!NGUARD || n < N) {
                        float v = acc[i][j][r];
                        ((float*)Cout)[(size_t)m * N + n] = v;
                        se += __expf(v);
                    }
                }
                se += __shfl_xor(se, 1); se += __shfl_xor(se, 2);
                se += __shfl_xor(se, 4); se += __shfl_xor(se, 8);
                if (fr == 0) part[(size_t)m * NPB + bn2] = se;
            }
        }
    } else {
        #pragma unroll
        for (int i = 0; i < 4; i++) {
            #pragma unroll
            for (int r = 0; r < 4; r++) {
                const int m = m0 + wr * 64 + i * 16 + crow + r;
                #pragma unroll
                for (int j = 0; j < 4; j++) {
                    const int n = n0 + wc * 64 + j * 16 + fr;
                    if (!NGUARD || n < N) {
                        float v = acc[i][j][r];
                        if (BIAS) v += bias[n];
                        if (GELU_) v = gelu_f(v);
                        if (RES_) v += res[(size_t)m * N + n];
                        if (OUTBF) ((__bf16*)Cout)[(size_t)m * N + n] = (__bf16)v;
                        else       ((float*)Cout)[(size_t)m * N + n] = v;
                    }
                }
            }
        }
    }
}

// ---------------------------------------------------------------- flash attention (bf16 MFMA)
__global__ __launch_bounds__(256) void fattn_kernel(
    const __bf16* __restrict__ qkv, __bf16* __restrict__ y)
{
    const int bq = blockIdx.x, h = blockIdx.y, b = blockIdx.z;
    const int tid = threadIdx.x, lane = tid & 63, w = tid >> 6;
    const int fr = lane & 15, g = lane >> 4;

    __shared__ __align__(16) __bf16 Ks[64 * 64];
    __shared__ __align__(16) __bf16 Vt[64 * 64];
    __shared__ __align__(16) __bf16 Ps[4][16 * 64];

    const __bf16* base = qkv + (size_t)b * TDIM * E3;
    const int q0w = bq * 64 + w * 16;

    bf16x8 qf[2];
    {
        const __bf16* qp = base + (size_t)(q0w + fr) * E3 + h * 64 + g * 8;
        qf[0] = *(const bf16x8*)qp;
        qf[1] = *(const bf16x8*)(qp + 32);
    }

    float m[4] = {-1e30f, -1e30f, -1e30f, -1e30f};
    float l[4] = {0.f, 0.f, 0.f, 0.f};
    f32x4 acc[4];
    #pragma unroll
    for (int jd = 0; jd < 4; ++jd) acc[jd] = (f32x4){0.f, 0.f, 0.f, 0.f};

    for (int kt = 0; kt <= bq; ++kt) {
        const int k0 = kt * 64;
        #pragma unroll
        for (int it = 0; it < 2; ++it) {
            const int s = tid + it * 256;
            const int row = s >> 3, ch = s & 7;
            const __bf16* gp = base + (size_t)(k0 + row) * E3 + EDIM + h * 64 + ch * 8;
            bf16x8 kv = *(const bf16x8*)gp;
            *(bf16x8*)(Ks + row * 64 + ((ch ^ (row & 7)) << 3)) = kv;
            bf16x8 vv = *(const bf16x8*)(gp + EDIM);
            #pragma unroll
            for (int j = 0; j < 8; ++j) {
                const int d = ch * 8 + j;
                const int key = ((d >> 3) ^ d) & 7;
                Vt[d * 64 + ((((row >> 3) ^ key) << 3) + (row & 7))] = vv[j];
            }
        }
        __syncthreads();

        f32x4 s[4];
        #pragma unroll
        for (int jf = 0; jf < 4; ++jf) {
            const int krow = jf * 16 + fr;
            f32x4 sv = (f32x4){0.f, 0.f, 0.f, 0.f};
            #pragma unroll
            for (int kc = 0; kc < 2; ++kc) {
                bf16x8 kf = *(const bf16x8*)(Ks + krow * 64 + (((kc * 4 + g) ^ (fr & 7)) << 3));
                sv = __builtin_amdgcn_mfma_f32_16x16x32_bf16(qf[kc], kf, sv, 0, 0, 0);
            }
            s[jf] = sv;
        }
        #pragma unroll
        for (int jf = 0; jf < 4; ++jf)
            #pragma unroll
            for (int r = 0; r < 4; ++r) s[jf][r] *= 0.125f;
        if (kt == bq) {
            #pragma unroll
            for (int jf = 0; jf < 4; ++jf) {
                const int k = k0 + jf * 16 + fr;
                #pragma unroll
                for (int r = 0; r < 4; ++r) {
                    const int q = q0w + g * 4 + r;
                    if (k > q) s[jf][r] = -1e30f;
                }
            }
        }

        #pragma unroll
        for (int r = 0; r < 4; ++r) {
            float mx = fmaxf(fmaxf(s[0][r], s[1][r]), fmaxf(s[2][r], s[3][r]));
            mx = fmaxf(mx, __shfl_xor(mx, 1));
            mx = fmaxf(mx, __shfl_xor(mx, 2));
            mx = fmaxf(mx, __shfl_xor(mx, 4));
            mx = fmaxf(mx, __shfl_xor(mx, 8));
            const float mn = fmaxf(m[r], mx);
            const float sc2 = __expf(m[r] - mn);
            m[r] = mn;
            float rs = 0.f;
            #pragma unroll
            for (int jf = 0; jf < 4; ++jf) {
                const float p = __expf(s[jf][r] - mn);
                s[jf][r] = p;
                rs += p;
            }
            rs += __shfl_xor(rs, 1);
            rs += __shfl_xor(rs, 2);
            rs += __shfl_xor(rs, 4);
            rs += __shfl_xor(rs, 8);
            l[r] = l[r] * sc2 + rs;
            #pragma unroll
            for (int jd = 0; jd < 4; ++jd) acc[jd][r] *= sc2;
        }

        __bf16* pw = &Ps[w][0];
        #pragma unroll
        for (int jf = 0; jf < 4; ++jf) {
            const int ch = jf * 2 + (fr >> 3);
            #pragma unroll
            for (int r = 0; r < 4; ++r) {
                const int row = g * 4 + r;
                pw[row * 64 + (((ch ^ (row & 7)) << 3) + (fr & 7))] = (__bf16)s[jf][r];
            }
        }
        asm volatile("s_waitcnt lgkmcnt(0)" ::: "memory");
        bf16x8 pa[2];
        #pragma unroll
        for (int kc = 0; kc < 2; ++kc)
            pa[kc] = *(const bf16x8*)(pw + fr * 64 + (((kc * 4 + g) ^ (fr & 7)) << 3));

        #pragma unroll
        for (int jd = 0; jd < 4; ++jd) {
            const int d = jd * 16 + fr;
            const int key = ((d >> 3) ^ d) & 7;
            #pragma unroll
            for (int kc = 0; kc < 2; ++kc) {
                bf16x8 vf = *(const bf16x8*)(Vt + d * 64 + (((kc * 4 + g) ^ key) << 3));
                acc[jd] = __builtin_amdgcn_mfma_f32_16x16x32_bf16(pa[kc], vf, acc[jd], 0, 0, 0);
            }
        }
        __syncthreads();
    }

    #pragma unroll
    for (int r = 0; r < 4; ++r) {
        const float inv = 1.0f / l[r];
        const int q = q0w + g * 4 + r;
        __bf16* yp = y + ((size_t)(b * TDIM + q)) * EDIM + h * 64;
        #pragma unroll
        for (int jd = 0; jd < 4; ++jd)
            yp[jd * 16 + fr] = (__bf16)(acc[jd][r] * inv);
    }
}

// ---------------------------------------------------------------- fused-LSE finalize
__global__ __launch_bounds__(256) void lsefin_kernel(
    const float* __restrict__ part, const float* __restrict__ logits,
    const int* __restrict__ targets, float* __restrict__ rr)
{
    const int row = blockIdx.x, tid = threadIdx.x;
    float s = 0.f;
    for (int j = tid; j < NPB; j += 256) s += part[(size_t)row * NPB + j];
    #pragma unroll
    for (int off = 32; off; off >>= 1) s += __shfl_xor(s, off);
    __shared__ float red[4];
    if ((tid & 63) == 0) red[tid >> 6] = s;
    __syncthreads();
    if (tid == 0) {
        float S = red[0] + red[1] + red[2] + red[3];
        rr[row] = logf(S) - logits[(size_t)row * VDIM + targets[row]];
    }
}

__global__ __launch_bounds__(256) void loss_reduce_kernel(
    const float* __restrict__ rr, float* __restrict__ out)
{
    const int tid = threadIdx.x;
    float s = 0.f;
    for (int i = tid; i < BT; i += 256) s += rr[i];
    #pragma unroll
    for (int off = 32; off; off >>= 1) s += __shfl_xor(s, off);
    __shared__ float red[4];
    if ((tid & 63) == 0) red[tid >> 6] = s;
    __syncthreads();
    if (tid == 0) out[0] = (red[0] + red[1] + red[2] + red[3]) * (1.0f / BT);
}

// ---------------------------------------------------------------- launch
extern "C" void kernel_launch(void* const* d_in, const int* in_sizes, int n_in,
                              void* d_out, int out_size, void* d_ws, size_t ws_size,
                              hipStream_t stream)
{
    const int*   idx     = (const int*)d_in[0];
    const int*   targets = (const int*)d_in[1];
    const float* wte     = (const float*)d_in[2];
    const float* wpe     = (const float*)d_in[3];
    const float* ln1_w   = (const float*)d_in[4];
    const float* ln1_b   = (const float*)d_in[5];
    const float* attn_w  = (const float*)d_in[6];
    const float* attn_b  = (const float*)d_in[7];
    const float* proj_w  = (const float*)d_in[8];
    const float* proj_b  = (const float*)d_in[9];
    const float* ln2_w   = (const float*)d_in[10];
    const float* ln2_b   = (const float*)d_in[11];
    const float* fc_w    = (const float*)d_in[12];
    const float* fc_b    = (const float*)d_in[13];
    const float* fcp_w   = (const float*)d_in[14];
    const float* fcp_b   = (const float*)d_in[15];
    const float* lnf_w   = (const float*)d_in[16];
    const float* lnf_b   = (const float*)d_in[17];

    float* logits = (float*)d_out;

    const size_t slq = (size_t)EDIM * E3, slp = (size_t)EDIM * EDIM;
    const size_t slf = (size_t)EDIM * E4, slfp = (size_t)E4 * EDIM;

    char* wp = (char*)d_ws;
    float*  x     = (float*)wp;   wp += (size_t)BT * EDIM * 4;
    __bf16* qkvb  = (__bf16*)wp;  wp += (size_t)BT * E3 * 2;
    __bf16* xnbf  = (__bf16*)wp;  wp += (size_t)BT * EDIM * 2;
    __bf16* ybf   = (__bf16*)wp;  wp += (size_t)BT * EDIM * 2;
    __bf16* hbf   = (__bf16*)wp;  wp += (size_t)BT * E4 * 2;
    __bf16* wteb  = (__bf16*)wp;  wp += (size_t)VDIM * EDIM * 2;
    float*  part  = (float*)wp;   wp += (size_t)BT * NPB * 4;
    float*  rr    = (float*)wp;   wp += (size_t)BT * 4;
    __bf16* wqkvb = (__bf16*)wp;

    const size_t wbytes_all = (slq + slp + slf + slfp) * 2 * LNUM;
    const size_t used = (size_t)(wp - (char*)d_ws);
    const bool big = ws_size >= used + wbytes_all;
    const size_t L = big ? LNUM : 1;
    __bf16* wprjb = wqkvb + slq * L;
    __bf16* wfcb  = wprjb + slp * L;
    __bf16* wfpb  = wfcb  + slf * L;

    embed_kernel<<<BT, 256, 0, stream>>>(idx, wte, wpe, x);
    cvt_kernel<<<2048, 256, 0, stream>>>(wte, wteb, (long)VDIM * EDIM / 4);

    if (big) {
        convt_kernel<<<dim3(E3 / 32, EDIM / 32, LNUM), 256, 0, stream>>>(attn_w, wqkvb, EDIM, E3);
        convt_kernel<<<dim3(EDIM / 32, EDIM / 32, LNUM), 256, 0, stream>>>(proj_w, wprjb, EDIM, EDIM);
        convt_kernel<<<dim3(E4 / 32, EDIM / 32, LNUM), 256, 0, stream>>>(fc_w, wfcb, EDIM, E4);
        convt_kernel<<<dim3(EDIM / 32, E4 / 32, LNUM), 256, 0, stream>>>(fcp_w, wfpb, E4, EDIM);
    }

    for (int l = 0; l < LNUM; ++l) {
        const __bf16* wq = wqkvb + (big ? (size_t)l * slq : 0);
        const __bf16* wpj = wprjb + (big ? (size_t)l * slp : 0);
        const __bf16* wf = wfcb + (big ? (size_t)l * slf : 0);
        const __bf16* wfp = wfpb + (big ? (size_t)l * slfp : 0);

        ln_kernel<<<BT, 256, 0, stream>>>(x, ln1_w + (size_t)l * EDIM,
                                          ln1_b + (size_t)l * EDIM, xnbf);
        if (!big)
            convt_kernel<<<dim3(E3 / 32, EDIM / 32), 256, 0, stream>>>(
                attn_w + (size_t)l * slq, (__bf16*)wq, EDIM, E3);
        mgemm<true, false, false, true, false, false><<<dim3(E3 / 128, BT / 128), 256, 0, stream>>>(
            xnbf, wq, attn_b + (size_t)l * E3, nullptr, qkvb, nullptr, BT, E3, EDIM);
        fattn_kernel<<<dim3(TDIM / 64, HNUM, BDIM), 256, 0, stream>>>(qkvb, ybf);
        if (!big)
            convt_kernel<<<dim3(EDIM / 32, EDIM / 32), 256, 0, stream>>>(
                proj_w + (size_t)l * slp, (__bf16*)wpj, EDIM, EDIM);
        mgemm<true, false, true, false, false, false><<<dim3(EDIM / 128, BT / 128), 256, 0, stream>>>(
            ybf, wpj, proj_b + (size_t)l * EDIM, x, x, nullptr, BT, EDIM, EDIM);
        ln_kernel<<<BT, 256, 0, stream>>>(x, ln2_w + (size_t)l * EDIM,
                                          ln2_b + (size_t)l * EDIM, xnbf);
        if (!big)
            convt_kernel<<<dim3(E4 / 32, EDIM / 32), 256, 0, stream>>>(
                fc_w + (size_t)l * slf, (__bf16*)wf, EDIM, E4);
        mgemm<true, true, false, true, false, false><<<dim3(E4 / 128, BT / 128), 256, 0, stream>>>(
            xnbf, wf, fc_b + (size_t)l * E4, nullptr, hbf, nullptr, BT, E4, EDIM);
        if (!big)
            convt_kernel<<<dim3(EDIM / 32, E4 / 32), 256, 0, stream>>>(
                fcp_w + (size_t)l * slfp, (__bf16*)wfp, E4, EDIM);
        mgemm<true, false, true, false, false, false><<<dim3(EDIM / 128, BT / 128), 256, 0, stream>>>(
            hbf, wfp, fcp_b + (size_t)l * EDIM, x, x, nullptr, BT, EDIM, E4);
    }

    ln_kernel<<<BT, 256, 0, stream>>>(x, lnf_w, lnf_b, xnbf);
    mgemm<false, false, false, false, true, true><<<dim3(BT / 128, (VDIM + 127) / 128), 256, 0, stream>>>(
        xnbf, wteb, nullptr, nullptr, logits, part, BT, VDIM, EDIM);
    lsefin_kernel<<<BT, 256, 0, stream>>>(part, logits, targets, rr);
    loss_reduce_kernel<<<1, 256, 0, stream>>>(rr, logits + (size_t)BT * VDIM);
}

// Round 6
// 2355.790 us; speedup vs baseline: 11.1666x; 1.1487x over previous
//
#include <hip/hip_runtime.h>
#include <hip/hip_bf16.h>
#include <math.h>

#define LNUM 12
#define HNUM 12
#define EDIM 768
#define VDIM 50257
#define BDIM 2
#define TDIM 1024
#define BT (BDIM*TDIM)
#define E3 (3*EDIM)
#define E4 (4*EDIM)
#define NPB (2*((VDIM+127)/128))   // 786 half-tile partials per row

typedef __bf16 bf16x8 __attribute__((ext_vector_type(8)));
typedef float f32x4 __attribute__((ext_vector_type(4)));

__device__ __forceinline__ float gelu_f(float x) {
    float u = 0.7978845608028654f * (x + 0.044715f * x * x * x);
    return 0.5f * x * (1.0f + tanhf(u));
}

// async global->LDS, 16B per lane
__device__ __forceinline__ void gl16(const void* g, void* l) {
    __builtin_amdgcn_global_load_lds(
        (const __attribute__((address_space(1))) unsigned int*)g,
        (__attribute__((address_space(3))) unsigned int*)l,
        16, 0, 0);
}

// ---------------------------------------------------------------- embedding
__global__ __launch_bounds__(256) void embed_kernel(
    const int* __restrict__ idx, const float* __restrict__ wte,
    const float* __restrict__ wpe, float* __restrict__ x)
{
    const int row = blockIdx.x;
    const int t = row % TDIM;
    const int tok = idx[row];
    const float* we = wte + (size_t)tok * EDIM;
    const float* pe = wpe + (size_t)t * EDIM;
    float* xr = x + (size_t)row * EDIM;
    for (int e = threadIdx.x; e < EDIM; e += 256) xr[e] = we[e] + pe[e];
}

// ---------------------------------------------------------------- layernorm (bf16 out)
__global__ __launch_bounds__(256) void ln_kernel(
    const float* __restrict__ in, const float* __restrict__ w,
    const float* __restrict__ b, __bf16* __restrict__ out)
{
    const int row = blockIdx.x, tid = threadIdx.x;
    const float* xr = in + (size_t)row * EDIM;
    float v0 = xr[tid], v1 = xr[tid + 256], v2 = xr[tid + 512];
    float s = v0 + v1 + v2;
    __shared__ float red[8];
    const int lane = tid & 63, wid = tid >> 6;
    #pragma unroll
    for (int off = 32; off; off >>= 1) s += __shfl_xor(s, off);
    if (lane == 0) red[wid] = s;
    __syncthreads();
    const float mean = (red[0] + red[1] + red[2] + red[3]) * (1.0f / EDIM);
    float d0 = v0 - mean, d1 = v1 - mean, d2 = v2 - mean;
    float s2 = d0 * d0 + d1 * d1 + d2 * d2;
    #pragma unroll
    for (int off = 32; off; off >>= 1) s2 += __shfl_xor(s2, off);
    if (lane == 0) red[4 + wid] = s2;
    __syncthreads();
    const float var = (red[4] + red[5] + red[6] + red[7]) * (1.0f / EDIM);
    const float inv = rsqrtf(var + 1e-5f);
    __bf16* orow = out + (size_t)row * EDIM;
    orow[tid]       = (__bf16)(d0 * inv * w[tid]       + b[tid]);
    orow[tid + 256] = (__bf16)(d1 * inv * w[tid + 256] + b[tid + 256]);
    orow[tid + 512] = (__bf16)(d2 * inv * w[tid + 512] + b[tid + 512]);
}

// ------------------------------------------------- weight convert: f32 [K][N] -> bf16 [N][K]
__global__ __launch_bounds__(256) void convt_kernel(
    const float* __restrict__ in, __bf16* __restrict__ out, int K, int N)
{
    in  += (size_t)blockIdx.z * K * N;
    out += (size_t)blockIdx.z * K * N;
    __shared__ float t[32][33];
    const int n0 = blockIdx.x * 32, k0 = blockIdx.y * 32;
    const int tx = threadIdx.x & 31, ty = threadIdx.x >> 5;
    #pragma unroll
    for (int r = ty; r < 32; r += 8)
        t[r][tx] = in[(size_t)(k0 + r) * N + n0 + tx];
    __syncthreads();
    #pragma unroll
    for (int r = ty; r < 32; r += 8)
        out[(size_t)(n0 + r) * K + k0 + tx] = (__bf16)t[tx][r];
}

// ------------------------------------------------- elementwise f32 -> bf16 (wte)
__global__ __launch_bounds__(256) void cvt_kernel(
    const float* __restrict__ in, __bf16* __restrict__ out, long n4)
{
    for (long i = blockIdx.x * 256L + threadIdx.x; i < n4; i += (long)gridDim.x * 256L) {
        float4 v = ((const float4*)in)[i];
        out[i * 4 + 0] = (__bf16)v.x;
        out[i * 4 + 1] = (__bf16)v.y;
        out[i * 4 + 2] = (__bf16)v.z;
        out[i * 4 + 3] = (__bf16)v.w;
    }
}

// ---------------------------------------------------------------- MFMA GEMM (2-phase dbuf)
// C[M,N] = act(A[M,K] @ Bt[N,K]^T + bias) (+res). A,Bt bf16 row-major (k-contiguous).
// BM x BN tile (128 or 64), BK=32, double-buffered LDS, one barrier per K-step.
// LOGITS: linear grid with XCD-bijective swizzle so the 16 M-blocks sharing a
// B-panel land on the same XCD's L2; writes f32 C + per-64-col sum-exp partials.
template<int BM, int BN, bool BIAS, bool GELU_, bool RES_, bool OUTBF, bool NGUARD, bool LOGITS>
__global__ __launch_bounds__(256) void mgemm(
    const __bf16* __restrict__ A, const __bf16* __restrict__ Bt,
    const float* __restrict__ bias, const float* __restrict__ res,
    void* __restrict__ Cout, float* __restrict__ part, int M, int N, int K)
{
    constexpr int WM = BM / 2, WN = BN / 2;         // per-wave output
    constexpr int FM = WM / 16, FN = WN / 16;       // frags per wave
    constexpr int rA = BM / 64, rB = BN / 64;       // staging rounds
    __shared__ __align__(16) __bf16 As[2 * BM * 32];
    __shared__ __align__(16) __bf16 Bs[2 * BN * 32];
    const int tid = threadIdx.x;
    const int lane = tid & 63;
    const int wave = tid >> 6;
    const int wr = wave >> 1, wc = wave & 1;

    int bm, bn;
    if (LOGITS) {
        const int wg = blockIdx.x;
        bn = (wg & 7) + ((wg >> 7) << 3);   // same XCD (wg%8) for all 16 bm of a bn
        bm = (wg >> 3) & 15;
        if (bn * 128 >= N) return;
    } else { bm = blockIdx.y; bn = blockIdx.x; }
    const int m0 = bm * BM;
    const int n0 = bn * BN;

    const int srow = tid >> 2;                       // 0..63
    const int c0 = (tid & 3) ^ ((srow >> 1) & 3);    // inverse-swizzled k-chunk

    const __bf16* gA = A + (size_t)(m0 + srow) * K + c0 * 8;
    const __bf16* gB[2];
    #pragma unroll
    for (int r = 0; r < rB; ++r) {
        int nr = n0 + srow + r * 64;
        if (NGUARD) nr = nr < N ? nr : N - 1;
        gB[r] = Bt + (size_t)nr * K + c0 * 8;
    }

    const int fr = lane & 15;
    const int g = lane >> 4;
    const int slot = ((g ^ ((lane >> 1) & 3)) << 4);
    const int offA = (wr * WM + fr) * 64 + slot;
    const int offB = (wc * WN + fr) * 64 + slot;

    f32x4 acc[FM][FN];
    #pragma unroll
    for (int i = 0; i < FM; i++)
        #pragma unroll
        for (int j = 0; j < FN; j++) acc[i][j] = (f32x4){0.f, 0.f, 0.f, 0.f};

    const int nt = K >> 5;
    // prologue: stage tile 0 into buf 0
    #pragma unroll
    for (int r = 0; r < rA; ++r)
        gl16(gA + (size_t)r * 64 * K, (char*)As + r * 4096 + tid * 16);
    #pragma unroll
    for (int r = 0; r < rB; ++r)
        gl16(gB[r], (char*)Bs + r * 4096 + tid * 16);
    __syncthreads();

    int buf = 0;
    for (int t = 0; t < nt; ++t) {
        if (t + 1 < nt) {
            const int k1 = (t + 1) << 5;
            #pragma unroll
            for (int r = 0; r < rA; ++r)
                gl16(gA + (size_t)r * 64 * K + k1, (char*)As + (buf ^ 1) * (BM * 64) + r * 4096 + tid * 16);
            #pragma unroll
            for (int r = 0; r < rB; ++r)
                gl16(gB[r] + k1, (char*)Bs + (buf ^ 1) * (BN * 64) + r * 4096 + tid * 16);
        }
        const char* pa = (const char*)As + buf * (BM * 64);
        const char* pb = (const char*)Bs + buf * (BN * 64);
        bf16x8 af[FM], bfr[FN];
        #pragma unroll
        for (int i = 0; i < FM; i++)
            af[i] = *(const bf16x8*)(pa + offA + i * 1024);
        #pragma unroll
        for (int j = 0; j < FN; j++)
            bfr[j] = *(const bf16x8*)(pb + offB + j * 1024);
        #pragma unroll
        for (int i = 0; i < FM; i++)
            #pragma unroll
            for (int j = 0; j < FN; j++)
                acc[i][j] = __builtin_amdgcn_mfma_f32_16x16x32_bf16(af[i], bfr[j], acc[i][j], 0, 0, 0);
        __syncthreads();   // drains vmcnt (next tile) + lgkm; one barrier per K-step
        buf ^= 1;
    }

    const int crow = g * 4;
    if (LOGITS) {
        const int bn2 = bn * 2 + wc;
        #pragma unroll
        for (int i = 0; i < FM; i++) {
            #pragma unroll
            for (int r = 0; r < 4; r++) {
                const int m = m0 + wr * WM + i * 16 + crow + r;
                float se = 0.f;
                #pragma unroll
                for (int j = 0; j < FN; j++) {
                    const int n = n0 + wc * WN + j * 16 + fr;
                    if (!NGUARD || n < N) {
                        float v = acc[i][j][r];
                        ((float*)Cout)[(size_t)m * N + n] = v;
                        se += __expf(v);
                    }
                }
                se += __shfl_xor(se, 1); se += __shfl_xor(se, 2);
                se += __shfl_xor(se, 4); se += __shfl_xor(se, 8);
                if (fr == 0) part[(size_t)m * NPB + bn2] = se;
            }
        }
    } else {
        #pragma unroll
        for (int i = 0; i < FM; i++) {
            #pragma unroll
            for (int r = 0; r < 4; r++) {
                const int m = m0 + wr * WM + i * 16 + crow + r;
                #pragma unroll
                for (int j = 0; j < FN; j++) {
                    const int n = n0 + wc * WN + j * 16 + fr;
                    if (!NGUARD || n < N) {
                        float v = acc[i][j][r];
                        if (BIAS) v += bias[n];
                        if (GELU_) v = gelu_f(v);
                        if (RES_) v += res[(size_t)m * N + n];
                        if (OUTBF) ((__bf16*)Cout)[(size_t)m * N + n] = (__bf16)v;
                        else       ((float*)Cout)[(size_t)m * N + n] = v;
                    }
                }
            }
        }
    }
}

// ---------------------------------------------------------------- flash attention (bf16 MFMA)
// T14 async-stage: next k-tile's K/V global loads issue into registers BEFORE
// the current tile's compute; LDS write happens after the post-compute barrier.
__global__ __launch_bounds__(256) void fattn_kernel(
    const __bf16* __restrict__ qkv, __bf16* __restrict__ y)
{
    const int bq = blockIdx.x, h = blockIdx.y, b = blockIdx.z;
    const int tid = threadIdx.x, lane = tid & 63, w = tid >> 6;
    const int fr = lane & 15, g = lane >> 4;

    __shared__ __align__(16) __bf16 Ks[64 * 64];
    __shared__ __align__(16) __bf16 Vt[64 * 64];
    __shared__ __align__(16) __bf16 Ps[4][16 * 64];

    const __bf16* base = qkv + (size_t)b * TDIM * E3;
    const int q0w = bq * 64 + w * 16;

    bf16x8 qf[2];
    {
        const __bf16* qp = base + (size_t)(q0w + fr) * E3 + h * 64 + g * 8;
        qf[0] = *(const bf16x8*)qp;
        qf[1] = *(const bf16x8*)(qp + 32);
    }

    const int r0 = tid >> 3, ch = tid & 7;   // staging coords: rows r0, r0+32; chunk ch
    bf16x8 kr[2], vr[2];

    // prologue: load tile 0 into regs, store to LDS
    #pragma unroll
    for (int it = 0; it < 2; ++it) {
        const int row = it * 32 + r0;
        const __bf16* gp = base + (size_t)row * E3 + EDIM + h * 64 + ch * 8;
        kr[it] = *(const bf16x8*)gp;
        vr[it] = *(const bf16x8*)(gp + EDIM);
    }
    #pragma unroll
    for (int it = 0; it < 2; ++it) {
        const int row = it * 32 + r0;
        *(bf16x8*)(Ks + row * 64 + ((ch ^ (row & 7)) << 3)) = kr[it];
        #pragma unroll
        for (int j = 0; j < 8; ++j) {
            const int d = ch * 8 + j;
            const int key = ((d >> 3) ^ d) & 7;
            Vt[d * 64 + ((((row >> 3) ^ key) << 3) + (row & 7))] = vr[it][j];
        }
    }
    __syncthreads();

    float m[4] = {-1e30f, -1e30f, -1e30f, -1e30f};
    float l[4] = {0.f, 0.f, 0.f, 0.f};
    f32x4 acc[4];
    #pragma unroll
    for (int jd = 0; jd < 4; ++jd) acc[jd] = (f32x4){0.f, 0.f, 0.f, 0.f};

    for (int kt = 0; kt <= bq; ++kt) {
        // issue next tile's global loads (latency hides under compute below)
        if (kt < bq) {
            const int k1 = (kt + 1) * 64;
            #pragma unroll
            for (int it = 0; it < 2; ++it) {
                const int row = it * 32 + r0;
                const __bf16* gp = base + (size_t)(k1 + row) * E3 + EDIM + h * 64 + ch * 8;
                kr[it] = *(const bf16x8*)gp;
                vr[it] = *(const bf16x8*)(gp + EDIM);
            }
        }

        const int k0 = kt * 64;
        f32x4 s[4];
        #pragma unroll
        for (int jf = 0; jf < 4; ++jf) {
            const int krow = jf * 16 + fr;
            f32x4 sv = (f32x4){0.f, 0.f, 0.f, 0.f};
            #pragma unroll
            for (int kc = 0; kc < 2; ++kc) {
                bf16x8 kf = *(const bf16x8*)(Ks + krow * 64 + (((kc * 4 + g) ^ (fr & 7)) << 3));
                sv = __builtin_amdgcn_mfma_f32_16x16x32_bf16(qf[kc], kf, sv, 0, 0, 0);
            }
            s[jf] = sv;
        }
        #pragma unroll
        for (int jf = 0; jf < 4; ++jf)
            #pragma unroll
            for (int r = 0; r < 4; ++r) s[jf][r] *= 0.125f;
        if (kt == bq) {
            #pragma unroll
            for (int jf = 0; jf < 4; ++jf) {
                const int k = k0 + jf * 16 + fr;
                #pragma unroll
                for (int r = 0; r < 4; ++r) {
                    const int q = q0w + g * 4 + r;
                    if (k > q) s[jf][r] = -1e30f;
                }
            }
        }

        #pragma unroll
        for (int r = 0; r < 4; ++r) {
            float mx = fmaxf(fmaxf(s[0][r], s[1][r]), fmaxf(s[2][r], s[3][r]));
            mx = fmaxf(mx, __shfl_xor(mx, 1));
            mx = fmaxf(mx, __shfl_xor(mx, 2));
            mx = fmaxf(mx, __shfl_xor(mx, 4));
            mx = fmaxf(mx, __shfl_xor(mx, 8));
            const float mn = fmaxf(m[r], mx);
            const float sc2 = __expf(m[r] - mn);
            m[r] = mn;
            float rs = 0.f;
            #pragma unroll
            for (int jf = 0; jf < 4; ++jf) {
                const float p = __expf(s[jf][r] - mn);
                s[jf][r] = p;
                rs += p;
            }
            rs += __shfl_xor(rs, 1);
            rs += __shfl_xor(rs, 2);
            rs += __shfl_xor(rs, 4);
            rs += __shfl_xor(rs, 8);
            l[r] = l[r] * sc2 + rs;
            #pragma unroll
            for (int jd = 0; jd < 4; ++jd) acc[jd][r] *= sc2;
        }

        __bf16* pw = &Ps[w][0];
        #pragma unroll
        for (int jf = 0; jf < 4; ++jf) {
            const int chp = jf * 2 + (fr >> 3);
            #pragma unroll
            for (int r = 0; r < 4; ++r) {
                const int row = g * 4 + r;
                pw[row * 64 + (((chp ^ (row & 7)) << 3) + (fr & 7))] = (__bf16)s[jf][r];
            }
        }
        asm volatile("s_waitcnt lgkmcnt(0)" ::: "memory");
        bf16x8 pa[2];
        #pragma unroll
        for (int kc = 0; kc < 2; ++kc)
            pa[kc] = *(const bf16x8*)(pw + fr * 64 + (((kc * 4 + g) ^ (fr & 7)) << 3));

        #pragma unroll
        for (int jd = 0; jd < 4; ++jd) {
            const int d = jd * 16 + fr;
            const int key = ((d >> 3) ^ d) & 7;
            #pragma unroll
            for (int kc = 0; kc < 2; ++kc) {
                bf16x8 vf = *(const bf16x8*)(Vt + d * 64 + (((kc * 4 + g) ^ key) << 3));
                acc[jd] = __builtin_amdgcn_mfma_f32_16x16x32_bf16(pa[kc], vf, acc[jd], 0, 0, 0);
            }
        }

        if (kt < bq) {          // uniform across block
            __syncthreads();    // everyone done reading Ks/Vt
            #pragma unroll
            for (int it = 0; it < 2; ++it) {
                const int row = it * 32 + r0;
                *(bf16x8*)(Ks + row * 64 + ((ch ^ (row & 7)) << 3)) = kr[it];
                #pragma unroll
                for (int j = 0; j < 8; ++j) {
                    const int d = ch * 8 + j;
                    const int key = ((d >> 3) ^ d) & 7;
                    Vt[d * 64 + ((((row >> 3) ^ key) << 3) + (row & 7))] = vr[it][j];
                }
            }
            __syncthreads();    // new tile visible
        }
    }

    #pragma unroll
    for (int r = 0; r < 4; ++r) {
        const float inv = 1.0f / l[r];
        const int q = q0w + g * 4 + r;
        __bf16* yp = y + ((size_t)(b * TDIM + q)) * EDIM + h * 64;
        #pragma unroll
        for (int jd = 0; jd < 4; ++jd)
            yp[jd * 16 + fr] = (__bf16)(acc[jd][r] * inv);
    }
}

// ---------------------------------------------------------------- fused-LSE finalize
__global__ __launch_bounds__(256) void lsefin_kernel(
    const float* __restrict__ part, const float* __restrict__ logits,
    const int* __restrict__ targets, float* __restrict__ rr)
{
    const int row = blockIdx.x, tid = threadIdx.x;
    float s = 0.f;
    for (int j = tid; j < NPB; j += 256) s += part[(size_t)row * NPB + j];
    #pragma unroll
    for (int off = 32; off; off >>= 1) s += __shfl_xor(s, off);
    __shared__ float red[4];
    if ((tid & 63) == 0) red[tid >> 6] = s;
    __syncthreads();
    if (tid == 0) {
        float S = red[0] + red[1] + red[2] + red[3];
        rr[row] = logf(S) - logits[(size_t)row * VDIM + targets[row]];
    }
}

__global__ __launch_bounds__(256) void loss_reduce_kernel(
    const float* __restrict__ rr, float* __restrict__ out)
{
    const int tid = threadIdx.x;
    float s = 0.f;
    for (int i = tid; i < BT; i += 256) s += rr[i];
    #pragma unroll
    for (int off = 32; off; off >>= 1) s += __shfl_xor(s, off);
    __shared__ float red[4];
    if ((tid & 63) == 0) red[tid >> 6] = s;
    __syncthreads();
    if (tid == 0) out[0] = (red[0] + red[1] + red[2] + red[3]) * (1.0f / BT);
}

// ---------------------------------------------------------------- launch
extern "C" void kernel_launch(void* const* d_in, const int* in_sizes, int n_in,
                              void* d_out, int out_size, void* d_ws, size_t ws_size,
                              hipStream_t stream)
{
    const int*   idx     = (const int*)d_in[0];
    const int*   targets = (const int*)d_in[1];
    const float* wte     = (const float*)d_in[2];
    const float* wpe     = (const float*)d_in[3];
    const float* ln1_w   = (const float*)d_in[4];
    const float* ln1_b   = (const float*)d_in[5];
    const float* attn_w  = (const float*)d_in[6];
    const float* attn_b  = (const float*)d_in[7];
    const float* proj_w  = (const float*)d_in[8];
    const float* proj_b  = (const float*)d_in[9];
    const float* ln2_w   = (const float*)d_in[10];
    const float* ln2_b   = (const float*)d_in[11];
    const float* fc_w    = (const float*)d_in[12];
    const float* fc_b    = (const float*)d_in[13];
    const float* fcp_w   = (const float*)d_in[14];
    const float* fcp_b   = (const float*)d_in[15];
    const float* lnf_w   = (const float*)d_in[16];
    const float* lnf_b   = (const float*)d_in[17];

    float* logits = (float*)d_out;

    const size_t slq = (size_t)EDIM * E3, slp = (size_t)EDIM * EDIM;
    const size_t slf = (size_t)EDIM * E4, slfp = (size_t)E4 * EDIM;

    char* wp = (char*)d_ws;
    float*  x     = (float*)wp;   wp += (size_t)BT * EDIM * 4;
    __bf16* qkvb  = (__bf16*)wp;  wp += (size_t)BT * E3 * 2;
    __bf16* xnbf  = (__bf16*)wp;  wp += (size_t)BT * EDIM * 2;
    __bf16* ybf   = (__bf16*)wp;  wp += (size_t)BT * EDIM * 2;
    __bf16* hbf   = (__bf16*)wp;  wp += (size_t)BT * E4 * 2;
    __bf16* wteb  = (__bf16*)wp;  wp += (size_t)VDIM * EDIM * 2;
    float*  part  = (float*)wp;   wp += (size_t)BT * NPB * 4;
    float*  rr    = (float*)wp;   wp += (size_t)BT * 4;
    __bf16* wqkvb = (__bf16*)wp;

    const size_t wbytes_all = (slq + slp + slf + slfp) * 2 * LNUM;
    const size_t used = (size_t)(wp - (char*)d_ws);
    const bool big = ws_size >= used + wbytes_all;
    const size_t L = big ? LNUM : 1;
    __bf16* wprjb = wqkvb + slq * L;
    __bf16* wfcb  = wprjb + slp * L;
    __bf16* wfpb  = wfcb  + slf * L;

    embed_kernel<<<BT, 256, 0, stream>>>(idx, wte, wpe, x);
    cvt_kernel<<<2048, 256, 0, stream>>>(wte, wteb, (long)VDIM * EDIM / 4);

    if (big) {
        convt_kernel<<<dim3(E3 / 32, EDIM / 32, LNUM), 256, 0, stream>>>(attn_w, wqkvb, EDIM, E3);
        convt_kernel<<<dim3(EDIM / 32, EDIM / 32, LNUM), 256, 0, stream>>>(proj_w, wprjb, EDIM, EDIM);
        convt_kernel<<<dim3(E4 / 32, EDIM / 32, LNUM), 256, 0, stream>>>(fc_w, wfcb, EDIM, E4);
        convt_kernel<<<dim3(EDIM / 32, E4 / 32, LNUM), 256, 0, stream>>>(fcp_w, wfpb, E4, EDIM);
    }

    for (int l = 0; l < LNUM; ++l) {
        const __bf16* wq = wqkvb + (big ? (size_t)l * slq : 0);
        const __bf16* wpj = wprjb + (big ? (size_t)l * slp : 0);
        const __bf16* wf = wfcb + (big ? (size_t)l * slf : 0);
        const __bf16* wfp = wfpb + (big ? (size_t)l * slfp : 0);

        ln_kernel<<<BT, 256, 0, stream>>>(x, ln1_w + (size_t)l * EDIM,
                                          ln1_b + (size_t)l * EDIM, xnbf);
        if (!big)
            convt_kernel<<<dim3(E3 / 32, EDIM / 32), 256, 0, stream>>>(
                attn_w + (size_t)l * slq, (__bf16*)wq, EDIM, E3);
        mgemm<128, 128, true, false, false, true, false, false>
            <<<dim3(E3 / 128, BT / 128), 256, 0, stream>>>(
            xnbf, wq, attn_b + (size_t)l * E3, nullptr, qkvb, nullptr, BT, E3, EDIM);
        fattn_kernel<<<dim3(TDIM / 64, HNUM, BDIM), 256, 0, stream>>>(qkvb, ybf);
        if (!big)
            convt_kernel<<<dim3(EDIM / 32, EDIM / 32), 256, 0, stream>>>(
                proj_w + (size_t)l * slp, (__bf16*)wpj, EDIM, EDIM);
        mgemm<64, 64, true, false, true, false, false, false>
            <<<dim3(EDIM / 64, BT / 64), 256, 0, stream>>>(
            ybf, wpj, proj_b + (size_t)l * EDIM, x, x, nullptr, BT, EDIM, EDIM);
        ln_kernel<<<BT, 256, 0, stream>>>(x, ln2_w + (size_t)l * EDIM,
                                          ln2_b + (size_t)l * EDIM, xnbf);
        if (!big)
            convt_kernel<<<dim3(E4 / 32, EDIM / 32), 256, 0, stream>>>(
                fc_w + (size_t)l * slf, (__bf16*)wf, EDIM, E4);
        mgemm<128, 128, true, true, false, true, false, false>
            <<<dim3(E4 / 128, BT / 128), 256, 0, stream>>>(
            xnbf, wf, fc_b + (size_t)l * E4, nullptr, hbf, nullptr, BT, E4, EDIM);
        if (!big)
            convt_kernel<<<dim3(EDIM / 32, E4 / 32), 256, 0, stream>>>(
                fcp_w + (size_t)l * slfp, (__bf16*)wfp, E4, EDIM);
        mgemm<64, 64, true, false, true, false, false, false>
            <<<dim3(EDIM / 64, BT / 64), 256, 0, stream>>>(
            hbf, wfp, fcp_b + (size_t)l * EDIM, x, x, nullptr, BT, EDIM, E4);
    }

    ln_kernel<<<BT, 256, 0, stream>>>(x, lnf_w, lnf_b, xnbf);
    // logits GEMM: XCD-swizzled linear grid (16 bm x 400 bn slots, guard inside)
    mgemm<128, 128, false, false, false, false, true, true>
        <<<dim3(16 * 400), 256, 0, stream>>>(
        xnbf, wteb, nullptr, nullptr, logits, part, BT, VDIM, EDIM);
    lsefin_kernel<<<BT, 256, 0, stream>>>(part, logits, targets, rr);
    loss_reduce_kernel<<<1, 256, 0, stream>>>(rr, logits + (size_t)BT * VDIM);
}